// Round 5
// baseline (1202.163 us; speedup 1.0000x reference)
//
#include <hip/hip_runtime.h>
#include <hip/hip_bf16.h>
#include <math.h>

#define N_NODES 50000
#define N_EDGES 1600000
#define DIN 128
#define NH 4
#define D1 100
#define P1 128   // padded per-head width for z1 (bf16)
#define D2 20
#define P2 32    // padded per-head width for z2 (bf16)
#define NB 64
#define EPS_BN 1e-5f

typedef unsigned int uint;
typedef unsigned short ushort;
typedef short short8v __attribute__((ext_vector_type(8)));
typedef float float4v __attribute__((ext_vector_type(4)));

__device__ __forceinline__ void bf16x2_unpack(uint p, float& lo, float& hi) {
  lo = __uint_as_float(p << 16);
  hi = __uint_as_float(p & 0xffff0000u);
}

__device__ __forceinline__ ushort f2bf(float f) {  // RNE, finite inputs
  uint u = __float_as_uint(f);
  return (ushort)((u + 0x7fffu + ((u >> 16) & 1u)) >> 16);
}

// ---------------------------------------------------------------------------
// Prep: B1t[h][j][k] bf16 (j padded to 128) from W1[h][k][j] fp32
// ---------------------------------------------------------------------------
__global__ void prep_b1t(const float* __restrict__ W1, ushort* __restrict__ B1t) {
  int o = blockIdx.x * 256 + threadIdx.x;  // 4*128*128 = 65536
  int h = o >> 14;
  int r = o & 16383;
  int j = r >> 7, k = r & 127;
  float v = (j < D1) ? W1[((size_t)h * DIN + k) * D1 + j] : 0.f;
  B1t[o] = f2bf(v);
}

// ---------------------------------------------------------------------------
// GEMM1 via bf16 MFMA 16x16x32: z1[row][h*128+j] = feat[row][:] . W1[h][:][j]
// Block = 64 rows x 128 cols (one head). 4 waves, each 16 rows x 128 cols.
// ---------------------------------------------------------------------------
__global__ __launch_bounds__(256) void gemm1_mfma(const float* __restrict__ feat,
                                                  const ushort* __restrict__ B1t,
                                                  ushort* __restrict__ z1b) {
  __shared__ short As[64 * 136];   // row stride 136 shorts = 272 B (16B-aligned)
  __shared__ short Bs[128 * 136];  // Bs[col][k]
  const int row0 = blockIdx.x * 64;
  const int h = blockIdx.y;
  const int tid = threadIdx.x;
  // stage A (fp32 -> bf16): 64 rows x 128 k = 2048 float4
#pragma unroll
  for (int it = 0; it < 8; it++) {
    int idx = tid + it * 256;
    int r = idx >> 5, c4 = idx & 31;
    int row = row0 + r;
    float4 v = make_float4(0.f, 0.f, 0.f, 0.f);
    if (row < N_NODES) v = *reinterpret_cast<const float4*>(feat + (size_t)row * DIN + c4 * 4);
    short4 s;
    s.x = (short)f2bf(v.x); s.y = (short)f2bf(v.y);
    s.z = (short)f2bf(v.z); s.w = (short)f2bf(v.w);
    *reinterpret_cast<short4*>(&As[r * 136 + c4 * 4]) = s;
  }
  // stage B: B1t[h] is [128 j][128 k] bf16 = 8192 uints, Bs[j][k]
  {
    const uint* bsrc = reinterpret_cast<const uint*>(B1t + (size_t)h * 16384);
#pragma unroll
    for (int it = 0; it < 32; it++) {
      int idx = tid + it * 256;
      int j = idx >> 6, kk = idx & 63;
      *reinterpret_cast<uint*>(&Bs[j * 136 + kk * 2]) = bsrc[idx];
    }
  }
  __syncthreads();
  const int wv = tid >> 6, lane = tid & 63;
  const int m = lane & 15, q = lane >> 4;
  float4v acc[8];
#pragma unroll
  for (int t = 0; t < 8; t++) acc[t] = (float4v){0.f, 0.f, 0.f, 0.f};
#pragma unroll
  for (int kq = 0; kq < 4; kq++) {
    short8v a = *reinterpret_cast<const short8v*>(&As[(wv * 16 + m) * 136 + kq * 32 + q * 8]);
#pragma unroll
    for (int t = 0; t < 8; t++) {
      short8v b = *reinterpret_cast<const short8v*>(&Bs[(t * 16 + m) * 136 + kq * 32 + q * 8]);
      acc[t] = __builtin_amdgcn_mfma_f32_16x16x32_bf16(a, b, acc[t], 0, 0, 0);
    }
  }
  // C/D: col = lane&15 (+16t), row = (lane>>4)*4 + reg
#pragma unroll
  for (int t = 0; t < 8; t++) {
    int col = h * P1 + t * 16 + m;
#pragma unroll
    for (int reg = 0; reg < 4; reg++) {
      int row = row0 + wv * 16 + q * 4 + reg;
      if (row < N_NODES) z1b[(size_t)row * (NH * P1) + col] = f2bf(acc[t][reg]);
    }
  }
}

// ---------------------------------------------------------------------------
// Vector fp32 GEMM -> bf16 head-padded output (layer 2: K=400, DOUT=20)
// ---------------------------------------------------------------------------
template <int K, int DOUT, int HEADS, int PAD>
__global__ __launch_bounds__(256) void gemm_heads_bf16(const float* __restrict__ A,
                                                       const float* __restrict__ W,
                                                       __hip_bfloat16* __restrict__ C,
                                                       int nrows) {
  constexpr int NC = HEADS * DOUT;
  constexpr int TM = 64, TN = 64, TK = 16;
  __shared__ __align__(16) float As[TK][TM + 4];
  __shared__ __align__(16) float Ws[TK][TN + 4];
  const int row0 = blockIdx.x * TM;
  const int col0 = blockIdx.y * TN;
  const int tid = threadIdx.x;
  const int tx = tid & 15, ty = tid >> 4;
  float acc[4][4] = {};
  for (int k0 = 0; k0 < K; k0 += TK) {
#pragma unroll
    for (int i = 0; i < 4; i++) {
      int r = (tid >> 4) + i * 16;
      int kk = tid & 15;
      int row = row0 + r;
      float v = 0.f;
      if (row < nrows) v = A[(size_t)row * K + k0 + kk];
      As[kk][r] = v;
    }
#pragma unroll
    for (int i = 0; i < 4; i++) {
      int kk = (tid >> 6) + i * 4;
      int cc = tid & 63;
      int c = col0 + cc;
      float v = 0.f;
      if (c < NC) {
        int h = c / DOUT, j = c % DOUT;
        v = W[((size_t)h * K + (k0 + kk)) * DOUT + j];
      }
      Ws[kk][cc] = v;
    }
    __syncthreads();
#pragma unroll
    for (int kk = 0; kk < TK; kk++) {
      float4 a4 = *reinterpret_cast<const float4*>(&As[kk][ty * 4]);
      float4 b4 = *reinterpret_cast<const float4*>(&Ws[kk][tx * 4]);
      acc[0][0] += a4.x * b4.x; acc[0][1] += a4.x * b4.y; acc[0][2] += a4.x * b4.z; acc[0][3] += a4.x * b4.w;
      acc[1][0] += a4.y * b4.x; acc[1][1] += a4.y * b4.y; acc[1][2] += a4.y * b4.z; acc[1][3] += a4.y * b4.w;
      acc[2][0] += a4.z * b4.x; acc[2][1] += a4.z * b4.y; acc[2][2] += a4.z * b4.z; acc[2][3] += a4.z * b4.w;
      acc[3][0] += a4.w * b4.x; acc[3][1] += a4.w * b4.y; acc[3][2] += a4.w * b4.z; acc[3][3] += a4.w * b4.w;
    }
    __syncthreads();
  }
#pragma unroll
  for (int i = 0; i < 4; i++) {
    int row = row0 + ty * 4 + i;
    if (row < nrows) {
#pragma unroll
      for (int j = 0; j < 4; j++) {
        int c = col0 + tx * 4 + j;
        if (c < NC) {
          int h = c / DOUT, cj = c % DOUT;
          C[(size_t)row * (HEADS * PAD) + h * PAD + cj] = __float2bfloat16(acc[i][j]);
        }
      }
    }
  }
}

// ---------------------------------------------------------------------------
// Attention scores from bf16 packed z. One thread per (node, head).
// ---------------------------------------------------------------------------
template <int DOUT, int PAD>
__global__ void scores_kernel(const __hip_bfloat16* __restrict__ z,
                              const float* __restrict__ a,
                              float* __restrict__ ssrc,
                              float* __restrict__ sdst) {
  int t = blockIdx.x * blockDim.x + threadIdx.x;
  if (t >= N_NODES * NH) return;
  int n = t >> 2;
  int h = t & 3;
  const uint* zr = reinterpret_cast<const uint*>(z) + (size_t)n * (NH * PAD / 2) + h * (PAD / 2);
  const float* as = a + h * 2 * DOUT;
  const float* ad = as + DOUT;
  float s1 = 0.f, s2 = 0.f;
  for (int j = 0; j < DOUT / 2; j++) {
    float lo, hi;
    bf16x2_unpack(zr[j], lo, hi);
    s1 += lo * as[2 * j] + hi * as[2 * j + 1];
    s2 += lo * ad[2 * j] + hi * ad[2 * j + 1];
  }
  ssrc[h * N_NODES + n] = s1;
  sdst[h * N_NODES + n] = s2;
}

// ---------------------------------------------------------------------------
// CSR build: histogram, 3-kernel hierarchical scan (+cursor), fill
// ---------------------------------------------------------------------------
__global__ void hist_kernel(const int* __restrict__ dst, int* __restrict__ cnt) {
  int e = blockIdx.x * blockDim.x + threadIdx.x;
  if (e < N_EDGES) atomicAdd(&cnt[dst[e]], 1);
}

__global__ __launch_bounds__(512) void scan1_kernel(const int* __restrict__ cnt,
                                                    int* __restrict__ row_ptr,
                                                    int* __restrict__ btot, int n) {
  __shared__ int ws[8];
  int b = blockIdx.x, tid = threadIdx.x, lane = tid & 63, wv = tid >> 6;
  int i = b * 512 + tid;
  int v = (i < n) ? cnt[i] : 0;
  int orig = v;
  for (int off = 1; off < 64; off <<= 1) {
    int t = __shfl_up(v, off);
    if (lane >= off) v += t;
  }
  if (lane == 63) ws[wv] = v;
  __syncthreads();
  int wo = 0;
  for (int j = 0; j < wv; j++) wo += ws[j];
  if (i < n) row_ptr[i] = wo + v - orig;
  if (tid == 511) btot[b] = wo + v;
}

__global__ __launch_bounds__(128) void scan2_kernel(int* __restrict__ btot,
                                                    int* __restrict__ row_ptr_n, int nb) {
  __shared__ int ws2[2];
  int tid = threadIdx.x, lane = tid & 63, wv = tid >> 6;
  int v = (tid < nb) ? btot[tid] : 0;
  int orig = v;
  for (int off = 1; off < 64; off <<= 1) {
    int t = __shfl_up(v, off);
    if (lane >= off) v += t;
  }
  if (lane == 63) ws2[wv] = v;
  __syncthreads();
  int wo = (wv == 1) ? ws2[0] : 0;
  if (tid < nb) btot[tid] = wo + v - orig;
  if (tid == nb - 1) *row_ptr_n = wo + v;
}

__global__ __launch_bounds__(512) void scan3_kernel(int* __restrict__ row_ptr,
                                                    int* __restrict__ cursor,
                                                    const int* __restrict__ btot, int n) {
  int i = blockIdx.x * 512 + threadIdx.x;
  if (i < n) {
    int v = row_ptr[i] + btot[blockIdx.x];
    row_ptr[i] = v;
    cursor[i] = v;
  }
}

__global__ void fill_kernel(const int* __restrict__ src, const int* __restrict__ dst,
                            int* __restrict__ cursor, int* __restrict__ csr_src,
                            int* __restrict__ csr_dst) {
  int e = blockIdx.x * blockDim.x + threadIdx.x;
  if (e < N_EDGES) {
    int d = dst[e];
    int p = atomicAdd(&cursor[d], 1);
    csr_src[p] = src[e];
    csr_dst[p] = d;
  }
}

// ---------------------------------------------------------------------------
// Edge-parallel softmax weights: w[h][p] = exp(leaky(ssrc[h][src]+sdst[h][dst]))
// ---------------------------------------------------------------------------
__global__ void weight_kernel(const float* __restrict__ ssrc,
                              const float* __restrict__ sdst,
                              const int* __restrict__ csr_src,
                              const int* __restrict__ csr_dst,
                              float* __restrict__ w) {
  int p = blockIdx.x * blockDim.x + threadIdx.x;
  if (p >= N_EDGES) return;
  int s = csr_src[p];
  int d = csr_dst[p];
#pragma unroll
  for (int h = 0; h < NH; h++) {
    float e = ssrc[h * N_NODES + s] + sdst[h * N_NODES + d];
    e = fmaxf(e, 0.01f * e);
    w[(size_t)h * N_EDGES + p] = __expf(e);
  }
}

// ---------------------------------------------------------------------------
// GAT layer 1 aggregation. Block = dst, wave = head. ILP-16 gather pipeline
// with prefetched (wave-uniform -> SGPR) csr/w loads.
// ---------------------------------------------------------------------------
__global__ __launch_bounds__(256) void agg1_kernel(const __hip_bfloat16* __restrict__ z,
                                                   const float* __restrict__ w,
                                                   const int* __restrict__ row_ptr,
                                                   const int* __restrict__ csr_src,
                                                   float* __restrict__ h1) {
  const int d = blockIdx.x;
  const int h = threadIdx.x >> 6, lane = threadIdx.x & 63;
  const int beg = row_ptr[d], end = row_ptr[d + 1];
  const int deg = end - beg;
  size_t obase = (size_t)d * (NH * D1) + h * D1;
  bool act = lane < D1 / 2;  // 50 lanes
  if (deg == 0) {
    if (act) *reinterpret_cast<float2*>(h1 + obase + 2 * lane) = make_float2(0.f, 0.f);
    return;
  }
  const float* wh = w + (size_t)h * N_EDGES;
  float den = 0.f;
  for (int i = lane; i < deg; i += 64) den += wh[beg + i];
#pragma unroll
  for (int off = 32; off > 0; off >>= 1) den += __shfl_xor(den, off);

  if (!act) return;
  const uint* zb = reinterpret_cast<const uint*>(z);
  const int STR = NH * P1 / 2;
  const int hco = h * (P1 / 2) + lane;
  float aE[4] = {0.f, 0.f, 0.f, 0.f};
  float aO[4] = {0.f, 0.f, 0.f, 0.f};
  int i = 0;
  if (deg >= 16) {
    int sA[16];
    float xA[16];
#pragma unroll
    for (int j = 0; j < 16; j++) { sA[j] = csr_src[beg + j]; xA[j] = wh[beg + j]; }
    for (;;) {
      uint pk[16];
#pragma unroll
      for (int j = 0; j < 16; j++) pk[j] = zb[(size_t)sA[j] * STR + hco];
      int nx = i + 16;
      bool more = (nx + 16 <= deg);
      int sN[16];
      float xN[16];
      if (more) {
#pragma unroll
        for (int j = 0; j < 16; j++) { sN[j] = csr_src[beg + nx + j]; xN[j] = wh[beg + nx + j]; }
      }
#pragma unroll
      for (int j = 0; j < 16; j++) {
        float lo, hi;
        bf16x2_unpack(pk[j], lo, hi);
        aE[j & 3] += xA[j] * lo;
        aO[j & 3] += xA[j] * hi;
      }
      i = nx;
      if (!more) break;
#pragma unroll
      for (int j = 0; j < 16; j++) { sA[j] = sN[j]; xA[j] = xN[j]; }
    }
  }
  for (; i + 4 <= deg; i += 4) {
    int s0 = csr_src[beg + i + 0], s1 = csr_src[beg + i + 1];
    int s2 = csr_src[beg + i + 2], s3 = csr_src[beg + i + 3];
    float x0 = wh[beg + i + 0], x1 = wh[beg + i + 1];
    float x2 = wh[beg + i + 2], x3 = wh[beg + i + 3];
    uint p0 = zb[(size_t)s0 * STR + hco];
    uint p1 = zb[(size_t)s1 * STR + hco];
    uint p2 = zb[(size_t)s2 * STR + hco];
    uint p3 = zb[(size_t)s3 * STR + hco];
    float lo, hi;
    bf16x2_unpack(p0, lo, hi); aE[0] += x0 * lo; aO[0] += x0 * hi;
    bf16x2_unpack(p1, lo, hi); aE[1] += x1 * lo; aO[1] += x1 * hi;
    bf16x2_unpack(p2, lo, hi); aE[2] += x2 * lo; aO[2] += x2 * hi;
    bf16x2_unpack(p3, lo, hi); aE[3] += x3 * lo; aO[3] += x3 * hi;
  }
  for (; i < deg; i++) {
    int s = csr_src[beg + i];
    float x = wh[beg + i];
    uint p = zb[(size_t)s * STR + hco];
    float lo, hi;
    bf16x2_unpack(p, lo, hi);
    aE[0] += x * lo;
    aO[0] += x * hi;
  }
  float inv = 1.0f / den;
  float vE = ((aE[0] + aE[1]) + (aE[2] + aE[3])) * inv;
  float vO = ((aO[0] + aO[1]) + (aO[2] + aO[3])) * inv;
  float2 o;
  o.x = vE > 0.f ? vE : 0.f;
  o.y = vO > 0.f ? vO : 0.f;
  *reinterpret_cast<float2*>(h1 + obase + 2 * lane) = o;
}

// ---------------------------------------------------------------------------
// GAT layer 2 aggregation + head-mean + relu + fused graph mean-pool atomics.
// Wave = head; 6 edge-groups x 10 lanes (col pair each), 4x unroll (24 deep).
// ---------------------------------------------------------------------------
__global__ __launch_bounds__(256) void agg2_kernel(const __hip_bfloat16* __restrict__ z,
                                                   const float* __restrict__ w,
                                                   const int* __restrict__ row_ptr,
                                                   const int* __restrict__ csr_src,
                                                   const int* __restrict__ gid,
                                                   float* __restrict__ hg,
                                                   int* __restrict__ gcnt) {
  __shared__ float hbuf[NH][D2];
  const int d = blockIdx.x;
  const int h = threadIdx.x >> 6, lane = threadIdx.x & 63;
  const int beg = row_ptr[d], end = row_ptr[d + 1];
  const int deg = end - beg;
  const int g = lane / 10;
  const int j = lane - g * 10;
  if (deg > 0) {
    const float* wh = w + (size_t)h * N_EDGES;
    float den = 0.f;
    for (int i = lane; i < deg; i += 64) den += wh[beg + i];
#pragma unroll
    for (int off = 32; off > 0; off >>= 1) den += __shfl_xor(den, off);

    const uint* zb = reinterpret_cast<const uint*>(z);
    const int STR2 = NH * P2 / 2;
    const int hco = h * (P2 / 2) + j;
    float aE = 0.f, aO = 0.f;
    if (g < 6) {
      int i = g;
      for (; i + 18 < deg; i += 24) {
        int s0 = csr_src[beg + i], s1 = csr_src[beg + i + 6];
        int s2 = csr_src[beg + i + 12], s3 = csr_src[beg + i + 18];
        float x0 = wh[beg + i], x1 = wh[beg + i + 6];
        float x2 = wh[beg + i + 12], x3 = wh[beg + i + 18];
        uint p0 = zb[(size_t)s0 * STR2 + hco];
        uint p1 = zb[(size_t)s1 * STR2 + hco];
        uint p2 = zb[(size_t)s2 * STR2 + hco];
        uint p3 = zb[(size_t)s3 * STR2 + hco];
        float lo, hi;
        bf16x2_unpack(p0, lo, hi); aE += x0 * lo; aO += x0 * hi;
        bf16x2_unpack(p1, lo, hi); aE += x1 * lo; aO += x1 * hi;
        bf16x2_unpack(p2, lo, hi); aE += x2 * lo; aO += x2 * hi;
        bf16x2_unpack(p3, lo, hi); aE += x3 * lo; aO += x3 * hi;
      }
      for (; i < deg; i += 6) {
        int s = csr_src[beg + i];
        float x = wh[beg + i];
        uint p = zb[(size_t)s * STR2 + hco];
        float lo, hi;
        bf16x2_unpack(p, lo, hi);
        aE += x * lo;
        aO += x * hi;
      }
    }
    float tE = aE, tO = aO;
#pragma unroll
    for (int k = 1; k < 6; k++) {
      tE += __shfl(aE, lane + 10 * k);
      tO += __shfl(aO, lane + 10 * k);
    }
    if (lane < 10) {
      float invd = 1.0f / den;
      hbuf[h][2 * j] = tE * invd;
      hbuf[h][2 * j + 1] = tO * invd;
    }
  } else {
    if (lane < 10) {
      hbuf[h][2 * j] = 0.f;
      hbuf[h][2 * j + 1] = 0.f;
    }
  }
  __syncthreads();
  if (threadIdx.x < D2) {
    int c = threadIdx.x;
    float m = 0.25f * (hbuf[0][c] + hbuf[1][c] + hbuf[2][c] + hbuf[3][c]);
    m = m > 0.f ? m : 0.f;
    atomicAdd(&hg[gid[d] * D2 + c], m);
  }
  if (threadIdx.x == 32) atomicAdd(&gcnt[gid[d]], 1);
}

// ---------------------------------------------------------------------------
// Readout MLP + BatchNorm + final projection in one block.
// ---------------------------------------------------------------------------
__global__ __launch_bounds__(256) void head_kernel(const float* __restrict__ hg,
                                                   const int* __restrict__ gcnt,
                                                   const float* __restrict__ Wf1,
                                                   const float* __restrict__ bf1,
                                                   const float* __restrict__ Wf2,
                                                   const float* __restrict__ bf2,
                                                   const float* __restrict__ Wf3,
                                                   const float* __restrict__ bf3,
                                                   const float* __restrict__ gamma,
                                                   const float* __restrict__ beta,
                                                   float* __restrict__ out) {
  __shared__ float X[NB][D2];
  __shared__ float T1[NB][128];
  __shared__ float T2[NB][32];
  __shared__ float scale_s[32], shift_s[32];
  int tid = threadIdx.x;
  for (int i = tid; i < NB * D2; i += 256) {
    int r = i / D2, c = i % D2;
    X[r][c] = hg[i] / (float)gcnt[r];
  }
  __syncthreads();
  for (int i = tid; i < NB * 128; i += 256) {
    int r = i >> 7, c = i & 127;
    float s = bf1[c];
#pragma unroll
    for (int k = 0; k < D2; k++) s += X[r][k] * Wf1[k * 128 + c];
    T1[r][c] = s > 0.f ? s : 0.f;
  }
  __syncthreads();
  for (int i = tid; i < NB * 32; i += 256) {
    int r = i >> 5, c = i & 31;
    float s = bf2[c];
#pragma unroll
    for (int k = 0; k < 128; k++) s += T1[r][k] * Wf2[k * 32 + c];
    T2[r][c] = s;
  }
  __syncthreads();
  if (tid < 32) {
    float mu = 0.f;
    for (int r = 0; r < NB; r++) mu += T2[r][tid];
    mu *= (1.f / NB);
    float var = 0.f;
    for (int r = 0; r < NB; r++) {
      float dv = T2[r][tid] - mu;
      var += dv * dv;
    }
    var *= (1.f / NB);
    float sc = gamma[tid] * rsqrtf(var + EPS_BN);
    scale_s[tid] = sc;
    shift_s[tid] = beta[tid] - mu * sc;
  }
  __syncthreads();
  if (tid < NB) {
    float s = bf3[0];
#pragma unroll
    for (int c = 0; c < 32; c++) {
      float y = scale_s[c] * T2[tid][c] + shift_s[c];
      y = y > 0.f ? y : 0.f;
      s += y * Wf3[c];
    }
    out[tid] = s;
  }
}

// ---------------------------------------------------------------------------

extern "C" void kernel_launch(void* const* d_in, const int* in_sizes, int n_in,
                              void* d_out, int out_size, void* d_ws, size_t ws_size,
                              hipStream_t stream) {
  const float* feat = (const float*)d_in[0];
  const int* src = (const int*)d_in[1];
  const int* dst = (const int*)d_in[2];
  const int* gid = (const int*)d_in[3];
  const float* W1 = (const float*)d_in[4];
  const float* a1 = (const float*)d_in[5];
  const float* W2 = (const float*)d_in[6];
  const float* a2 = (const float*)d_in[7];
  const float* Wf1 = (const float*)d_in[8];
  const float* bf1 = (const float*)d_in[9];
  const float* Wf2 = (const float*)d_in[10];
  const float* bf2 = (const float*)d_in[11];
  const float* Wf3 = (const float*)d_in[12];
  const float* bf3 = (const float*)d_in[13];
  const float* gamma2 = (const float*)d_in[14];
  const float* beta2 = (const float*)d_in[15];
  float* outp = (float*)d_out;

  char* p = (char*)d_ws;
  auto alloc = [&](size_t bytes) {
    void* q = (void*)p;
    p += (bytes + 255) & ~(size_t)255;
    return q;
  };
  __hip_bfloat16* z1b = (__hip_bfloat16*)alloc((size_t)N_NODES * NH * P1 * 2);  // 51.2 MB
  __hip_bfloat16* z2b = (__hip_bfloat16*)alloc((size_t)N_NODES * NH * P2 * 2);  // 12.8 MB
  float* h1 = (float*)alloc((size_t)N_NODES * NH * D1 * 4);                      // 80 MB
  float* ssrc = (float*)alloc((size_t)NH * N_NODES * 4);
  float* sdst = (float*)alloc((size_t)NH * N_NODES * 4);
  float* wbuf = (float*)alloc((size_t)NH * N_EDGES * 4);                         // 25.6 MB
  int* cnt = (int*)alloc((size_t)N_NODES * 4);
  int* row_ptr = (int*)alloc((size_t)(N_NODES + 1) * 4);
  int* cursor = (int*)alloc((size_t)N_NODES * 4);
  int* csr = (int*)alloc((size_t)N_EDGES * 4);
  int* csr_d = (int*)alloc((size_t)N_EDGES * 4);
  int* btot = (int*)alloc((size_t)128 * 4);
  ushort* B1t = (ushort*)alloc((size_t)NH * 128 * 128 * 2);                      // 128 KB
  float* hg = (float*)alloc((size_t)NB * D2 * 4);                                // 5120 B slot
  int* gcnt = (int*)alloc((size_t)NB * 4);                                       // adjacent to hg

  const int rows64 = (N_NODES + 63) / 64;        // 782
  const int eblk = (N_EDGES + 255) / 256;        // 6250
  const int nhblk = (N_NODES * NH + 255) / 256;  // 782
  const int sblk = (N_NODES + 511) / 512;        // 98

  // CSR build
  hipMemsetAsync(cnt, 0, (size_t)N_NODES * 4, stream);
  hist_kernel<<<eblk, 256, 0, stream>>>(dst, cnt);
  scan1_kernel<<<sblk, 512, 0, stream>>>(cnt, row_ptr, btot, N_NODES);
  scan2_kernel<<<1, 128, 0, stream>>>(btot, row_ptr + N_NODES, sblk);
  scan3_kernel<<<sblk, 512, 0, stream>>>(row_ptr, cursor, btot, N_NODES);
  fill_kernel<<<eblk, 256, 0, stream>>>(src, dst, cursor, csr, csr_d);

  // Layer 1 (MFMA GEMM)
  prep_b1t<<<256, 256, 0, stream>>>(W1, B1t);
  gemm1_mfma<<<dim3(rows64, NH), 256, 0, stream>>>(feat, B1t, (ushort*)z1b);
  scores_kernel<D1, P1><<<nhblk, 256, 0, stream>>>(z1b, a1, ssrc, sdst);
  weight_kernel<<<eblk, 256, 0, stream>>>(ssrc, sdst, csr, csr_d, wbuf);
  agg1_kernel<<<N_NODES, 256, 0, stream>>>(z1b, wbuf, row_ptr, csr, h1);

  // Layer 2
  gemm_heads_bf16<NH * D1, D2, NH, P2><<<dim3(rows64, 2), 256, 0, stream>>>(h1, W2, z2b, N_NODES);
  scores_kernel<D2, P2><<<nhblk, 256, 0, stream>>>(z2b, a2, ssrc, sdst);
  weight_kernel<<<eblk, 256, 0, stream>>>(ssrc, sdst, csr, csr_d, wbuf);
  hipMemsetAsync(hg, 0, (size_t)(NB * D2 * 4 + 256), stream);  // hg + gcnt (adjacent)
  agg2_kernel<<<N_NODES, 256, 0, stream>>>(z2b, wbuf, row_ptr, csr, gid, hg, gcnt);

  // Readout
  head_kernel<<<1, 256, 0, stream>>>(hg, gcnt, Wf1, bf1, Wf2, bf2, Wf3, bf3,
                                     gamma2, beta2, outp);
}

// Round 6
// 904.145 us; speedup vs baseline: 1.3296x; 1.3296x over previous
//
#include <hip/hip_runtime.h>
#include <hip/hip_bf16.h>
#include <math.h>

#define N_NODES 50000
#define N_EDGES 1600000
#define DIN 128
#define NH 4
#define D1 100
#define P1 128   // padded per-head width for z1 (bf16)
#define D2 20
#define P2 32    // padded per-head width for z2 (bf16)
#define NB 64
#define EPS_BN 1e-5f

typedef unsigned int uint;
typedef unsigned short ushort;
typedef short short8v __attribute__((ext_vector_type(8)));
typedef float float4v __attribute__((ext_vector_type(4)));

__device__ __forceinline__ void bf16x2_unpack(uint p, float& lo, float& hi) {
  lo = __uint_as_float(p << 16);
  hi = __uint_as_float(p & 0xffff0000u);
}

__device__ __forceinline__ ushort f2bf(float f) {  // RNE, finite inputs
  uint u = __float_as_uint(f);
  return (ushort)((u + 0x7fffu + ((u >> 16) & 1u)) >> 16);
}

// ---------------------------------------------------------------------------
// Prep: B1t[h][j][k] bf16 (j padded to 128) from W1[h][k][j] fp32
// ---------------------------------------------------------------------------
__global__ void prep_b1t(const float* __restrict__ W1, ushort* __restrict__ B1t) {
  int o = blockIdx.x * 256 + threadIdx.x;  // 4*128*128 = 65536
  int h = o >> 14;
  int r = o & 16383;
  int j = r >> 7, k = r & 127;
  float v = (j < D1) ? W1[((size_t)h * DIN + k) * D1 + j] : 0.f;
  B1t[o] = f2bf(v);
}

// ---------------------------------------------------------------------------
// GEMM1 via bf16 MFMA 16x16x32: z1[row][h*128+j] = feat[row][:] . W1[h][:][j]
// Block = 64 rows x 128 cols (one head). 4 waves, each 16 rows x 128 cols.
// ---------------------------------------------------------------------------
__global__ __launch_bounds__(256) void gemm1_mfma(const float* __restrict__ feat,
                                                  const ushort* __restrict__ B1t,
                                                  ushort* __restrict__ z1b) {
  __shared__ short As[64 * 136];   // row stride 136 shorts = 272 B (16B-aligned)
  __shared__ short Bs[128 * 136];  // Bs[col][k]
  const int row0 = blockIdx.x * 64;
  const int h = blockIdx.y;
  const int tid = threadIdx.x;
  // stage A (fp32 -> bf16): 64 rows x 128 k = 2048 float4
#pragma unroll
  for (int it = 0; it < 8; it++) {
    int idx = tid + it * 256;
    int r = idx >> 5, c4 = idx & 31;
    int row = row0 + r;
    float4 v = make_float4(0.f, 0.f, 0.f, 0.f);
    if (row < N_NODES) v = *reinterpret_cast<const float4*>(feat + (size_t)row * DIN + c4 * 4);
    short4 s;
    s.x = (short)f2bf(v.x); s.y = (short)f2bf(v.y);
    s.z = (short)f2bf(v.z); s.w = (short)f2bf(v.w);
    *reinterpret_cast<short4*>(&As[r * 136 + c4 * 4]) = s;
  }
  // stage B: B1t[h] is [128 j][128 k] bf16 = 8192 uints, Bs[j][k]
  {
    const uint* bsrc = reinterpret_cast<const uint*>(B1t + (size_t)h * 16384);
#pragma unroll
    for (int it = 0; it < 32; it++) {
      int idx = tid + it * 256;
      int j = idx >> 6, kk = idx & 63;
      *reinterpret_cast<uint*>(&Bs[j * 136 + kk * 2]) = bsrc[idx];
    }
  }
  __syncthreads();
  const int wv = tid >> 6, lane = tid & 63;
  const int m = lane & 15, q = lane >> 4;
  float4v acc[8];
#pragma unroll
  for (int t = 0; t < 8; t++) acc[t] = (float4v){0.f, 0.f, 0.f, 0.f};
#pragma unroll
  for (int kq = 0; kq < 4; kq++) {
    short8v a = *reinterpret_cast<const short8v*>(&As[(wv * 16 + m) * 136 + kq * 32 + q * 8]);
#pragma unroll
    for (int t = 0; t < 8; t++) {
      short8v b = *reinterpret_cast<const short8v*>(&Bs[(t * 16 + m) * 136 + kq * 32 + q * 8]);
      acc[t] = __builtin_amdgcn_mfma_f32_16x16x32_bf16(a, b, acc[t], 0, 0, 0);
    }
  }
  // C/D: col = lane&15 (+16t), row = (lane>>4)*4 + reg
#pragma unroll
  for (int t = 0; t < 8; t++) {
    int col = h * P1 + t * 16 + m;
#pragma unroll
    for (int reg = 0; reg < 4; reg++) {
      int row = row0 + wv * 16 + q * 4 + reg;
      if (row < N_NODES) z1b[(size_t)row * (NH * P1) + col] = f2bf(acc[t][reg]);
    }
  }
}

// ---------------------------------------------------------------------------
// Vector fp32 GEMM -> bf16 head-padded output (layer 2: K=400, DOUT=20)
// ---------------------------------------------------------------------------
template <int K, int DOUT, int HEADS, int PAD>
__global__ __launch_bounds__(256) void gemm_heads_bf16(const float* __restrict__ A,
                                                       const float* __restrict__ W,
                                                       __hip_bfloat16* __restrict__ C,
                                                       int nrows) {
  constexpr int NC = HEADS * DOUT;
  constexpr int TM = 64, TN = 64, TK = 16;
  __shared__ __align__(16) float As[TK][TM + 4];
  __shared__ __align__(16) float Ws[TK][TN + 4];
  const int row0 = blockIdx.x * TM;
  const int col0 = blockIdx.y * TN;
  const int tid = threadIdx.x;
  const int tx = tid & 15, ty = tid >> 4;
  float acc[4][4] = {};
  for (int k0 = 0; k0 < K; k0 += TK) {
#pragma unroll
    for (int i = 0; i < 4; i++) {
      int r = (tid >> 4) + i * 16;
      int kk = tid & 15;
      int row = row0 + r;
      float v = 0.f;
      if (row < nrows) v = A[(size_t)row * K + k0 + kk];
      As[kk][r] = v;
    }
#pragma unroll
    for (int i = 0; i < 4; i++) {
      int kk = (tid >> 6) + i * 4;
      int cc = tid & 63;
      int c = col0 + cc;
      float v = 0.f;
      if (c < NC) {
        int h = c / DOUT, j = c % DOUT;
        v = W[((size_t)h * K + (k0 + kk)) * DOUT + j];
      }
      Ws[kk][cc] = v;
    }
    __syncthreads();
#pragma unroll
    for (int kk = 0; kk < TK; kk++) {
      float4 a4 = *reinterpret_cast<const float4*>(&As[kk][ty * 4]);
      float4 b4 = *reinterpret_cast<const float4*>(&Ws[kk][tx * 4]);
      acc[0][0] += a4.x * b4.x; acc[0][1] += a4.x * b4.y; acc[0][2] += a4.x * b4.z; acc[0][3] += a4.x * b4.w;
      acc[1][0] += a4.y * b4.x; acc[1][1] += a4.y * b4.y; acc[1][2] += a4.y * b4.z; acc[1][3] += a4.y * b4.w;
      acc[2][0] += a4.z * b4.x; acc[2][1] += a4.z * b4.y; acc[2][2] += a4.z * b4.z; acc[2][3] += a4.z * b4.w;
      acc[3][0] += a4.w * b4.x; acc[3][1] += a4.w * b4.y; acc[3][2] += a4.w * b4.z; acc[3][3] += a4.w * b4.w;
    }
    __syncthreads();
  }
#pragma unroll
  for (int i = 0; i < 4; i++) {
    int row = row0 + ty * 4 + i;
    if (row < nrows) {
#pragma unroll
      for (int j = 0; j < 4; j++) {
        int c = col0 + tx * 4 + j;
        if (c < NC) {
          int h = c / DOUT, cj = c % DOUT;
          C[(size_t)row * (HEADS * PAD) + h * PAD + cj] = __float2bfloat16(acc[i][j]);
        }
      }
    }
  }
}

// ---------------------------------------------------------------------------
// Attention scores from bf16 packed z. One thread per (node, head).
// ---------------------------------------------------------------------------
template <int DOUT, int PAD>
__global__ void scores_kernel(const __hip_bfloat16* __restrict__ z,
                              const float* __restrict__ a,
                              float* __restrict__ ssrc,
                              float* __restrict__ sdst) {
  int t = blockIdx.x * blockDim.x + threadIdx.x;
  if (t >= N_NODES * NH) return;
  int n = t >> 2;
  int h = t & 3;
  const uint* zr = reinterpret_cast<const uint*>(z) + (size_t)n * (NH * PAD / 2) + h * (PAD / 2);
  const float* as = a + h * 2 * DOUT;
  const float* ad = as + DOUT;
  float s1 = 0.f, s2 = 0.f;
  for (int j = 0; j < DOUT / 2; j++) {
    float lo, hi;
    bf16x2_unpack(zr[j], lo, hi);
    s1 += lo * as[2 * j] + hi * as[2 * j + 1];
    s2 += lo * ad[2 * j] + hi * ad[2 * j + 1];
  }
  ssrc[h * N_NODES + n] = s1;
  sdst[h * N_NODES + n] = s2;
}

// ---------------------------------------------------------------------------
// CSR build: histogram, 3-kernel hierarchical scan (+cursor), fill
// ---------------------------------------------------------------------------
__global__ void hist_kernel(const int* __restrict__ dst, int* __restrict__ cnt) {
  int e = blockIdx.x * blockDim.x + threadIdx.x;
  if (e < N_EDGES) atomicAdd(&cnt[dst[e]], 1);
}

__global__ __launch_bounds__(512) void scan1_kernel(const int* __restrict__ cnt,
                                                    int* __restrict__ row_ptr,
                                                    int* __restrict__ btot, int n) {
  __shared__ int ws[8];
  int b = blockIdx.x, tid = threadIdx.x, lane = tid & 63, wv = tid >> 6;
  int i = b * 512 + tid;
  int v = (i < n) ? cnt[i] : 0;
  int orig = v;
  for (int off = 1; off < 64; off <<= 1) {
    int t = __shfl_up(v, off);
    if (lane >= off) v += t;
  }
  if (lane == 63) ws[wv] = v;
  __syncthreads();
  int wo = 0;
  for (int j = 0; j < wv; j++) wo += ws[j];
  if (i < n) row_ptr[i] = wo + v - orig;
  if (tid == 511) btot[b] = wo + v;
}

__global__ __launch_bounds__(128) void scan2_kernel(int* __restrict__ btot,
                                                    int* __restrict__ row_ptr_n, int nb) {
  __shared__ int ws2[2];
  int tid = threadIdx.x, lane = tid & 63, wv = tid >> 6;
  int v = (tid < nb) ? btot[tid] : 0;
  int orig = v;
  for (int off = 1; off < 64; off <<= 1) {
    int t = __shfl_up(v, off);
    if (lane >= off) v += t;
  }
  if (lane == 63) ws2[wv] = v;
  __syncthreads();
  int wo = (wv == 1) ? ws2[0] : 0;
  if (tid < nb) btot[tid] = wo + v - orig;
  if (tid == nb - 1) *row_ptr_n = wo + v;
}

__global__ __launch_bounds__(512) void scan3_kernel(int* __restrict__ row_ptr,
                                                    int* __restrict__ cursor,
                                                    const int* __restrict__ btot, int n) {
  int i = blockIdx.x * 512 + threadIdx.x;
  if (i < n) {
    int v = row_ptr[i] + btot[blockIdx.x];
    row_ptr[i] = v;
    cursor[i] = v;
  }
}

__global__ void fill_kernel(const int* __restrict__ src, const int* __restrict__ dst,
                            int* __restrict__ cursor, int* __restrict__ csr_src,
                            int* __restrict__ csr_dst) {
  int e = blockIdx.x * blockDim.x + threadIdx.x;
  if (e < N_EDGES) {
    int d = dst[e];
    int p = atomicAdd(&cursor[d], 1);
    csr_src[p] = src[e];
    csr_dst[p] = d;
  }
}

// ---------------------------------------------------------------------------
// Edge-parallel softmax weights: w[h][p] = exp(leaky(ssrc[h][src]+sdst[h][dst]))
// ---------------------------------------------------------------------------
__global__ void weight_kernel(const float* __restrict__ ssrc,
                              const float* __restrict__ sdst,
                              const int* __restrict__ csr_src,
                              const int* __restrict__ csr_dst,
                              float* __restrict__ w) {
  int p = blockIdx.x * blockDim.x + threadIdx.x;
  if (p >= N_EDGES) return;
  int s = csr_src[p];
  int d = csr_dst[p];
#pragma unroll
  for (int h = 0; h < NH; h++) {
    float e = ssrc[h * N_NODES + s] + sdst[h * N_NODES + d];
    e = fmaxf(e, 0.01f * e);
    w[(size_t)h * N_EDGES + p] = __expf(e);
  }
}

// ---------------------------------------------------------------------------
// GAT layer 1 aggregation. Block = dst, wave = head. ILP-16 gather pipeline
// with prefetched (wave-uniform -> SGPR) csr/w loads.
// ---------------------------------------------------------------------------
__global__ __launch_bounds__(256) void agg1_kernel(const __hip_bfloat16* __restrict__ z,
                                                   const float* __restrict__ w,
                                                   const int* __restrict__ row_ptr,
                                                   const int* __restrict__ csr_src,
                                                   float* __restrict__ h1) {
  const int d = blockIdx.x;
  const int h = threadIdx.x >> 6, lane = threadIdx.x & 63;
  const int beg = row_ptr[d], end = row_ptr[d + 1];
  const int deg = end - beg;
  size_t obase = (size_t)d * (NH * D1) + h * D1;
  bool act = lane < D1 / 2;  // 50 lanes
  if (deg == 0) {
    if (act) *reinterpret_cast<float2*>(h1 + obase + 2 * lane) = make_float2(0.f, 0.f);
    return;
  }
  const float* wh = w + (size_t)h * N_EDGES;
  float den = 0.f;
  for (int i = lane; i < deg; i += 64) den += wh[beg + i];
#pragma unroll
  for (int off = 32; off > 0; off >>= 1) den += __shfl_xor(den, off);

  if (!act) return;
  const uint* zb = reinterpret_cast<const uint*>(z);
  const int STR = NH * P1 / 2;
  const int hco = h * (P1 / 2) + lane;
  float aE[4] = {0.f, 0.f, 0.f, 0.f};
  float aO[4] = {0.f, 0.f, 0.f, 0.f};
  int i = 0;
  if (deg >= 16) {
    int sA[16];
    float xA[16];
#pragma unroll
    for (int j = 0; j < 16; j++) { sA[j] = csr_src[beg + j]; xA[j] = wh[beg + j]; }
    for (;;) {
      uint pk[16];
#pragma unroll
      for (int j = 0; j < 16; j++) pk[j] = zb[(size_t)sA[j] * STR + hco];
      int nx = i + 16;
      bool more = (nx + 16 <= deg);
      int sN[16];
      float xN[16];
      if (more) {
#pragma unroll
        for (int j = 0; j < 16; j++) { sN[j] = csr_src[beg + nx + j]; xN[j] = wh[beg + nx + j]; }
      }
#pragma unroll
      for (int j = 0; j < 16; j++) {
        float lo, hi;
        bf16x2_unpack(pk[j], lo, hi);
        aE[j & 3] += xA[j] * lo;
        aO[j & 3] += xA[j] * hi;
      }
      i = nx;
      if (!more) break;
#pragma unroll
      for (int j = 0; j < 16; j++) { sA[j] = sN[j]; xA[j] = xN[j]; }
    }
  }
  for (; i + 4 <= deg; i += 4) {
    int s0 = csr_src[beg + i + 0], s1 = csr_src[beg + i + 1];
    int s2 = csr_src[beg + i + 2], s3 = csr_src[beg + i + 3];
    float x0 = wh[beg + i + 0], x1 = wh[beg + i + 1];
    float x2 = wh[beg + i + 2], x3 = wh[beg + i + 3];
    uint p0 = zb[(size_t)s0 * STR + hco];
    uint p1 = zb[(size_t)s1 * STR + hco];
    uint p2 = zb[(size_t)s2 * STR + hco];
    uint p3 = zb[(size_t)s3 * STR + hco];
    float lo, hi;
    bf16x2_unpack(p0, lo, hi); aE[0] += x0 * lo; aO[0] += x0 * hi;
    bf16x2_unpack(p1, lo, hi); aE[1] += x1 * lo; aO[1] += x1 * hi;
    bf16x2_unpack(p2, lo, hi); aE[2] += x2 * lo; aO[2] += x2 * hi;
    bf16x2_unpack(p3, lo, hi); aE[3] += x3 * lo; aO[3] += x3 * hi;
  }
  for (; i < deg; i++) {
    int s = csr_src[beg + i];
    float x = wh[beg + i];
    uint p = zb[(size_t)s * STR + hco];
    float lo, hi;
    bf16x2_unpack(p, lo, hi);
    aE[0] += x * lo;
    aO[0] += x * hi;
  }
  float inv = 1.0f / den;
  float vE = ((aE[0] + aE[1]) + (aE[2] + aE[3])) * inv;
  float vO = ((aO[0] + aO[1]) + (aO[2] + aO[3])) * inv;
  float2 o;
  o.x = vE > 0.f ? vE : 0.f;
  o.y = vO > 0.f ? vO : 0.f;
  *reinterpret_cast<float2*>(h1 + obase + 2 * lane) = o;
}

// ---------------------------------------------------------------------------
// GAT layer 2 aggregation + head-mean + relu (writes h2; pooling separate).
// Wave = head; 6 edge-groups x 10 lanes (col pair each), 2x unroll (12 deep).
// ---------------------------------------------------------------------------
__global__ __launch_bounds__(256) void agg2_kernel(const __hip_bfloat16* __restrict__ z,
                                                   const float* __restrict__ w,
                                                   const int* __restrict__ row_ptr,
                                                   const int* __restrict__ csr_src,
                                                   float* __restrict__ h2) {
  __shared__ float hbuf[NH][D2];
  const int d = blockIdx.x;
  const int h = threadIdx.x >> 6, lane = threadIdx.x & 63;
  const int beg = row_ptr[d], end = row_ptr[d + 1];
  const int deg = end - beg;
  const int g = lane / 10;
  const int j = lane - g * 10;
  if (deg > 0) {
    const float* wh = w + (size_t)h * N_EDGES;
    float den = 0.f;
    for (int i = lane; i < deg; i += 64) den += wh[beg + i];
#pragma unroll
    for (int off = 32; off > 0; off >>= 1) den += __shfl_xor(den, off);

    const uint* zb = reinterpret_cast<const uint*>(z);
    const int STR2 = NH * P2 / 2;
    const int hco = h * (P2 / 2) + j;
    float aE = 0.f, aO = 0.f;
    if (g < 6) {
      int i = g;
      for (; i + 6 < deg; i += 12) {
        int s0 = csr_src[beg + i];
        int s1 = csr_src[beg + i + 6];
        float x0 = wh[beg + i];
        float x1 = wh[beg + i + 6];
        uint p0 = zb[(size_t)s0 * STR2 + hco];
        uint p1 = zb[(size_t)s1 * STR2 + hco];
        float lo, hi;
        bf16x2_unpack(p0, lo, hi); aE += x0 * lo; aO += x0 * hi;
        bf16x2_unpack(p1, lo, hi); aE += x1 * lo; aO += x1 * hi;
      }
      if (i < deg) {
        int s = csr_src[beg + i];
        float x = wh[beg + i];
        uint p = zb[(size_t)s * STR2 + hco];
        float lo, hi;
        bf16x2_unpack(p, lo, hi);
        aE += x * lo;
        aO += x * hi;
      }
    }
    float tE = aE, tO = aO;
#pragma unroll
    for (int k = 1; k < 6; k++) {
      tE += __shfl(aE, lane + 10 * k);
      tO += __shfl(aO, lane + 10 * k);
    }
    if (lane < 10) {
      float invd = 1.0f / den;
      hbuf[h][2 * j] = tE * invd;
      hbuf[h][2 * j + 1] = tO * invd;
    }
  } else {
    if (lane < 10) {
      hbuf[h][2 * j] = 0.f;
      hbuf[h][2 * j + 1] = 0.f;
    }
  }
  __syncthreads();
  if (threadIdx.x < D2) {
    int c = threadIdx.x;
    float m = 0.25f * (hbuf[0][c] + hbuf[1][c] + hbuf[2][c] + hbuf[3][c]);
    h2[(size_t)d * D2 + c] = m > 0.f ? m : 0.f;
  }
}

// ---------------------------------------------------------------------------
// Graph mean-pool: wave-level pre-reduction (graph_id is sorted) -> ~15k
// atomics total instead of 1M (R5's fused version serialized on 80 lines).
// ---------------------------------------------------------------------------
__global__ __launch_bounds__(256) void pool_kernel(const float* __restrict__ h2,
                                                   const int* __restrict__ gid,
                                                   float* __restrict__ hg,
                                                   int* __restrict__ gcnt) {
  int wave = threadIdx.x >> 6, lane = threadIdx.x & 63;
  int n = (blockIdx.x * 4 + wave) * 64 + lane;
  bool valid = n < N_NODES;
  int g = gid[valid ? n : (N_NODES - 1)];
  int g0 = __shfl(g, 0), g63 = __shfl(g, 63);
  unsigned long long mask = __ballot(valid);
  if (g0 == g63) {
    if (lane == 0) atomicAdd(&gcnt[g0], (int)__popcll(mask));
#pragma unroll
    for (int c = 0; c < D2; c++) {
      float v = valid ? h2[(size_t)n * D2 + c] : 0.f;
#pragma unroll
      for (int off = 32; off > 0; off >>= 1) v += __shfl_xor(v, off);
      if (lane == 0) atomicAdd(&hg[g0 * D2 + c], v);
    }
  } else if (valid) {
    atomicAdd(&gcnt[g], 1);
    for (int c = 0; c < D2; c++) atomicAdd(&hg[g * D2 + c], h2[(size_t)n * D2 + c]);
  }
}

// ---------------------------------------------------------------------------
// Readout MLP + BatchNorm + final projection in one block.
// ---------------------------------------------------------------------------
__global__ __launch_bounds__(256) void head_kernel(const float* __restrict__ hg,
                                                   const int* __restrict__ gcnt,
                                                   const float* __restrict__ Wf1,
                                                   const float* __restrict__ bf1,
                                                   const float* __restrict__ Wf2,
                                                   const float* __restrict__ bf2,
                                                   const float* __restrict__ Wf3,
                                                   const float* __restrict__ bf3,
                                                   const float* __restrict__ gamma,
                                                   const float* __restrict__ beta,
                                                   float* __restrict__ out) {
  __shared__ float X[NB][D2];
  __shared__ float T1[NB][128];
  __shared__ float T2[NB][32];
  __shared__ float scale_s[32], shift_s[32];
  int tid = threadIdx.x;
  for (int i = tid; i < NB * D2; i += 256) {
    int r = i / D2, c = i % D2;
    X[r][c] = hg[i] / (float)gcnt[r];
  }
  __syncthreads();
  for (int i = tid; i < NB * 128; i += 256) {
    int r = i >> 7, c = i & 127;
    float s = bf1[c];
#pragma unroll
    for (int k = 0; k < D2; k++) s += X[r][k] * Wf1[k * 128 + c];
    T1[r][c] = s > 0.f ? s : 0.f;
  }
  __syncthreads();
  for (int i = tid; i < NB * 32; i += 256) {
    int r = i >> 5, c = i & 31;
    float s = bf2[c];
#pragma unroll
    for (int k = 0; k < 128; k++) s += T1[r][k] * Wf2[k * 32 + c];
    T2[r][c] = s;
  }
  __syncthreads();
  if (tid < 32) {
    float mu = 0.f;
    for (int r = 0; r < NB; r++) mu += T2[r][tid];
    mu *= (1.f / NB);
    float var = 0.f;
    for (int r = 0; r < NB; r++) {
      float dv = T2[r][tid] - mu;
      var += dv * dv;
    }
    var *= (1.f / NB);
    float sc = gamma[tid] * rsqrtf(var + EPS_BN);
    scale_s[tid] = sc;
    shift_s[tid] = beta[tid] - mu * sc;
  }
  __syncthreads();
  if (tid < NB) {
    float s = bf3[0];
#pragma unroll
    for (int c = 0; c < 32; c++) {
      float y = scale_s[c] * T2[tid][c] + shift_s[c];
      y = y > 0.f ? y : 0.f;
      s += y * Wf3[c];
    }
    out[tid] = s;
  }
}

// ---------------------------------------------------------------------------

extern "C" void kernel_launch(void* const* d_in, const int* in_sizes, int n_in,
                              void* d_out, int out_size, void* d_ws, size_t ws_size,
                              hipStream_t stream) {
  const float* feat = (const float*)d_in[0];
  const int* src = (const int*)d_in[1];
  const int* dst = (const int*)d_in[2];
  const int* gid = (const int*)d_in[3];
  const float* W1 = (const float*)d_in[4];
  const float* a1 = (const float*)d_in[5];
  const float* W2 = (const float*)d_in[6];
  const float* a2 = (const float*)d_in[7];
  const float* Wf1 = (const float*)d_in[8];
  const float* bf1 = (const float*)d_in[9];
  const float* Wf2 = (const float*)d_in[10];
  const float* bf2 = (const float*)d_in[11];
  const float* Wf3 = (const float*)d_in[12];
  const float* bf3 = (const float*)d_in[13];
  const float* gamma2 = (const float*)d_in[14];
  const float* beta2 = (const float*)d_in[15];
  float* outp = (float*)d_out;

  char* p = (char*)d_ws;
  auto alloc = [&](size_t bytes) {
    void* q = (void*)p;
    p += (bytes + 255) & ~(size_t)255;
    return q;
  };
  __hip_bfloat16* z1b = (__hip_bfloat16*)alloc((size_t)N_NODES * NH * P1 * 2);  // 51.2 MB
  __hip_bfloat16* z2b = (__hip_bfloat16*)alloc((size_t)N_NODES * NH * P2 * 2);  // 12.8 MB
  float* h1 = (float*)alloc((size_t)N_NODES * NH * D1 * 4);                      // 80 MB
  float* ssrc = (float*)alloc((size_t)NH * N_NODES * 4);
  float* sdst = (float*)alloc((size_t)NH * N_NODES * 4);
  float* wbuf = (float*)alloc((size_t)NH * N_EDGES * 4);                         // 25.6 MB
  int* cnt = (int*)alloc((size_t)N_NODES * 4);
  int* row_ptr = (int*)alloc((size_t)(N_NODES + 1) * 4);
  int* cursor = (int*)alloc((size_t)N_NODES * 4);
  int* csr = (int*)alloc((size_t)N_EDGES * 4);
  int* csr_d = (int*)alloc((size_t)N_EDGES * 4);
  int* btot = (int*)alloc((size_t)128 * 4);
  ushort* B1t = (ushort*)alloc((size_t)NH * 128 * 128 * 2);                      // 128 KB
  float* hg = (float*)alloc((size_t)NB * D2 * 4);
  int* gcnt = (int*)alloc((size_t)NB * 4);
  float* h2 = h1;  // reuse

  const int rows64 = (N_NODES + 63) / 64;        // 782
  const int eblk = (N_EDGES + 255) / 256;        // 6250
  const int nblk = (N_NODES + 255) / 256;        // 196
  const int nhblk = (N_NODES * NH + 255) / 256;  // 782
  const int sblk = (N_NODES + 511) / 512;        // 98

  // CSR build
  hipMemsetAsync(cnt, 0, (size_t)N_NODES * 4, stream);
  hist_kernel<<<eblk, 256, 0, stream>>>(dst, cnt);
  scan1_kernel<<<sblk, 512, 0, stream>>>(cnt, row_ptr, btot, N_NODES);
  scan2_kernel<<<1, 128, 0, stream>>>(btot, row_ptr + N_NODES, sblk);
  scan3_kernel<<<sblk, 512, 0, stream>>>(row_ptr, cursor, btot, N_NODES);
  fill_kernel<<<eblk, 256, 0, stream>>>(src, dst, cursor, csr, csr_d);

  // Layer 1 (MFMA GEMM)
  prep_b1t<<<256, 256, 0, stream>>>(W1, B1t);
  gemm1_mfma<<<dim3(rows64, NH), 256, 0, stream>>>(feat, B1t, (ushort*)z1b);
  scores_kernel<D1, P1><<<nhblk, 256, 0, stream>>>(z1b, a1, ssrc, sdst);
  weight_kernel<<<eblk, 256, 0, stream>>>(ssrc, sdst, csr, csr_d, wbuf);
  agg1_kernel<<<N_NODES, 256, 0, stream>>>(z1b, wbuf, row_ptr, csr, h1);

  // Layer 2
  gemm_heads_bf16<NH * D1, D2, NH, P2><<<dim3(rows64, 2), 256, 0, stream>>>(h1, W2, z2b, N_NODES);
  scores_kernel<D2, P2><<<nhblk, 256, 0, stream>>>(z2b, a2, ssrc, sdst);
  weight_kernel<<<eblk, 256, 0, stream>>>(ssrc, sdst, csr, csr_d, wbuf);
  agg2_kernel<<<N_NODES, 256, 0, stream>>>(z2b, wbuf, row_ptr, csr, h2);

  // Readout
  hipMemsetAsync(hg, 0, (size_t)NB * D2 * 4, stream);
  hipMemsetAsync(gcnt, 0, (size_t)NB * 4, stream);
  pool_kernel<<<nblk, 256, 0, stream>>>(h2, gid, hg, gcnt);
  head_kernel<<<1, 256, 0, stream>>>(hg, gcnt, Wf1, bf1, Wf2, bf2, Wf3, bf3,
                                     gamma2, beta2, outp);
}

// Round 7
// 798.096 us; speedup vs baseline: 1.5063x; 1.1329x over previous
//
#include <hip/hip_runtime.h>
#include <hip/hip_bf16.h>
#include <math.h>

#define N_NODES 50000
#define N_EDGES 1600000
#define DIN 128
#define NH 4
#define D1 100
#define D2 20
#define NB 64
#define EPS_BN 1e-5f

// z1: [node][NH*D1=400] bf16 unpadded (800 B rows, 13 lines/edge across 4 heads)
// z2: [node][NH*D2=80]  bf16 unpadded (160 B rows, 3 lines/edge)
// h1: [node][400] bf16 (feeds MFMA GEMM2 directly)

typedef unsigned int uint;
typedef unsigned short ushort;
typedef short short8v __attribute__((ext_vector_type(8)));
typedef float float4v __attribute__((ext_vector_type(4)));

__device__ __forceinline__ void bf16x2_unpack(uint p, float& lo, float& hi) {
  lo = __uint_as_float(p << 16);
  hi = __uint_as_float(p & 0xffff0000u);
}

__device__ __forceinline__ ushort f2bf(float f) {  // RNE, finite inputs
  uint u = __float_as_uint(f);
  return (ushort)((u + 0x7fffu + ((u >> 16) & 1u)) >> 16);
}

// ---------------------------------------------------------------------------
// Prep: B1t[h][j][k] bf16 (j padded to 128) from W1[h][k][j] fp32
// ---------------------------------------------------------------------------
__global__ void prep_b1t(const float* __restrict__ W1, ushort* __restrict__ B1t) {
  int o = blockIdx.x * 256 + threadIdx.x;  // 4*128*128 = 65536
  int h = o >> 14;
  int r = o & 16383;
  int j = r >> 7, k = r & 127;
  float v = (j < D1) ? W1[((size_t)h * DIN + k) * D1 + j] : 0.f;
  B1t[o] = f2bf(v);
}

// ---------------------------------------------------------------------------
// Prep: B2t[c][k] bf16, c = h*20+j (80 cols), K padded 400->416 with zeros
// ---------------------------------------------------------------------------
__global__ void prep_b2t(const float* __restrict__ W2, ushort* __restrict__ B2t) {
  int idx = blockIdx.x * 256 + threadIdx.x;  // 80*416 = 33280
  if (idx >= 80 * 416) return;
  int c = idx / 416, k = idx - c * 416;
  int h = c / D2, j = c - h * D2;
  float v = (k < NH * D1) ? W2[((size_t)h * (NH * D1) + k) * D2 + j] : 0.f;
  B2t[idx] = f2bf(v);
}

// ---------------------------------------------------------------------------
// GEMM1 via bf16 MFMA 16x16x32: z1[row][h*100+j] = feat[row][:] . W1[h][:][j]
// Block = 64 rows x 128 cols (one head, cols>=100 dropped at store).
// ---------------------------------------------------------------------------
__global__ __launch_bounds__(256) void gemm1_mfma(const float* __restrict__ feat,
                                                  const ushort* __restrict__ B1t,
                                                  ushort* __restrict__ z1b) {
  __shared__ __align__(16) short As[64 * 136];
  __shared__ __align__(16) short Bs[128 * 136];
  const int row0 = blockIdx.x * 64;
  const int h = blockIdx.y;
  const int tid = threadIdx.x;
#pragma unroll
  for (int it = 0; it < 8; it++) {
    int idx = tid + it * 256;
    int r = idx >> 5, c4 = idx & 31;
    int row = row0 + r;
    float4 v = make_float4(0.f, 0.f, 0.f, 0.f);
    if (row < N_NODES) v = *reinterpret_cast<const float4*>(feat + (size_t)row * DIN + c4 * 4);
    short4 s;
    s.x = (short)f2bf(v.x); s.y = (short)f2bf(v.y);
    s.z = (short)f2bf(v.z); s.w = (short)f2bf(v.w);
    *reinterpret_cast<short4*>(&As[r * 136 + c4 * 4]) = s;
  }
  {
    const uint* bsrc = reinterpret_cast<const uint*>(B1t + (size_t)h * 16384);
#pragma unroll
    for (int it = 0; it < 32; it++) {
      int idx = tid + it * 256;
      int j = idx >> 6, kk = idx & 63;
      *reinterpret_cast<uint*>(&Bs[j * 136 + kk * 2]) = bsrc[idx];
    }
  }
  __syncthreads();
  const int wv = tid >> 6, lane = tid & 63;
  const int m = lane & 15, q = lane >> 4;
  float4v acc[8];
#pragma unroll
  for (int t = 0; t < 8; t++) acc[t] = (float4v){0.f, 0.f, 0.f, 0.f};
#pragma unroll
  for (int kq = 0; kq < 4; kq++) {
    short8v a = *reinterpret_cast<const short8v*>(&As[(wv * 16 + m) * 136 + kq * 32 + q * 8]);
#pragma unroll
    for (int t = 0; t < 8; t++) {
      short8v b = *reinterpret_cast<const short8v*>(&Bs[(t * 16 + m) * 136 + kq * 32 + q * 8]);
      acc[t] = __builtin_amdgcn_mfma_f32_16x16x32_bf16(a, b, acc[t], 0, 0, 0);
    }
  }
  // C/D: col = t*16 + (lane&15), row = (lane>>4)*4 + reg; drop col >= 100
#pragma unroll
  for (int t = 0; t < 8; t++) {
    int cl = t * 16 + m;
    if (cl < D1) {
#pragma unroll
      for (int reg = 0; reg < 4; reg++) {
        int row = row0 + wv * 16 + q * 4 + reg;
        if (row < N_NODES) z1b[(size_t)row * (NH * D1) + h * D1 + cl] = f2bf(acc[t][reg]);
      }
    }
  }
}

// ---------------------------------------------------------------------------
// GEMM2 via bf16 MFMA: z2[row][c] = h1[row][:400] . B2t[c][:], c < 80.
// Block = 64 rows x 80 cols, 13 K-chunks of 32.
// ---------------------------------------------------------------------------
__global__ __launch_bounds__(256) void gemm2_mfma(const ushort* __restrict__ h1b,
                                                  const ushort* __restrict__ B2t,
                                                  ushort* __restrict__ z2b) {
  __shared__ __align__(16) short As[64 * 40];  // row stride 40 shorts = 80 B
  __shared__ __align__(16) short Bs[80 * 40];
  const int row0 = blockIdx.x * 64;
  const int tid = threadIdx.x;
  const int wv = tid >> 6, lane = tid & 63;
  const int m = lane & 15, q = lane >> 4;
  const uint* au = reinterpret_cast<const uint*>(h1b);
  const uint* bu = reinterpret_cast<const uint*>(B2t);
  uint* asu = reinterpret_cast<uint*>(As);
  uint* bsu = reinterpret_cast<uint*>(Bs);
  float4v acc[5];
#pragma unroll
  for (int t = 0; t < 5; t++) acc[t] = (float4v){0.f, 0.f, 0.f, 0.f};
  for (int ch = 0; ch < 13; ch++) {
    int k0u = ch * 16;  // uint offset within row (200 uints total)
    {
      int idx = tid;  // A: 64x16 uints
#pragma unroll
      for (int it = 0; it < 4; it++, idx += 256) {
        int r = idx >> 4, ku = idx & 15;
        int row = row0 + r;
        uint v = 0;
        if (row < N_NODES && (k0u + ku) < 200) v = au[(size_t)row * 200 + k0u + ku];
        asu[r * 20 + ku] = v;
      }
      idx = tid;  // B: 80x16 uints (B2t rows are 208 uints, zero-padded)
#pragma unroll
      for (int it = 0; it < 5; it++, idx += 256) {
        int c = idx >> 4, ku = idx & 15;
        bsu[c * 20 + ku] = bu[(size_t)c * 208 + k0u + ku];
      }
    }
    __syncthreads();
    short8v a = *reinterpret_cast<const short8v*>(&As[(wv * 16 + m) * 40 + q * 8]);
#pragma unroll
    for (int t = 0; t < 5; t++) {
      short8v b = *reinterpret_cast<const short8v*>(&Bs[(t * 16 + m) * 40 + q * 8]);
      acc[t] = __builtin_amdgcn_mfma_f32_16x16x32_bf16(a, b, acc[t], 0, 0, 0);
    }
    __syncthreads();
  }
#pragma unroll
  for (int t = 0; t < 5; t++) {
    int col = t * 16 + m;
#pragma unroll
    for (int reg = 0; reg < 4; reg++) {
      int row = row0 + wv * 16 + q * 4 + reg;
      if (row < N_NODES) z2b[(size_t)row * (NH * D2) + col] = f2bf(acc[t][reg]);
    }
  }
}

// ---------------------------------------------------------------------------
// Attention scores from bf16 packed z (unpadded rows). Thread per (node,head).
// ---------------------------------------------------------------------------
template <int DOUT>
__global__ void scores_kernel(const ushort* __restrict__ z,
                              const float* __restrict__ a,
                              float* __restrict__ ssrc,
                              float* __restrict__ sdst) {
  int t = blockIdx.x * blockDim.x + threadIdx.x;
  if (t >= N_NODES * NH) return;
  int n = t >> 2;
  int h = t & 3;
  const uint* zr = reinterpret_cast<const uint*>(z) + (size_t)n * (NH * DOUT / 2) + h * (DOUT / 2);
  const float* as = a + h * 2 * DOUT;
  const float* ad = as + DOUT;
  float s1 = 0.f, s2 = 0.f;
  for (int j = 0; j < DOUT / 2; j++) {
    float lo, hi;
    bf16x2_unpack(zr[j], lo, hi);
    s1 += lo * as[2 * j] + hi * as[2 * j + 1];
    s2 += lo * ad[2 * j] + hi * ad[2 * j + 1];
  }
  ssrc[h * N_NODES + n] = s1;
  sdst[h * N_NODES + n] = s2;
}

// ---------------------------------------------------------------------------
// CSR build: histogram, 3-kernel hierarchical scan (+cursor), fill
// ---------------------------------------------------------------------------
__global__ void hist_kernel(const int* __restrict__ dst, int* __restrict__ cnt) {
  int e = blockIdx.x * blockDim.x + threadIdx.x;
  if (e < N_EDGES) atomicAdd(&cnt[dst[e]], 1);
}

__global__ __launch_bounds__(512) void scan1_kernel(const int* __restrict__ cnt,
                                                    int* __restrict__ row_ptr,
                                                    int* __restrict__ btot, int n) {
  __shared__ int ws[8];
  int b = blockIdx.x, tid = threadIdx.x, lane = tid & 63, wv = tid >> 6;
  int i = b * 512 + tid;
  int v = (i < n) ? cnt[i] : 0;
  int orig = v;
  for (int off = 1; off < 64; off <<= 1) {
    int t = __shfl_up(v, off);
    if (lane >= off) v += t;
  }
  if (lane == 63) ws[wv] = v;
  __syncthreads();
  int wo = 0;
  for (int j = 0; j < wv; j++) wo += ws[j];
  if (i < n) row_ptr[i] = wo + v - orig;
  if (tid == 511) btot[b] = wo + v;
}

__global__ __launch_bounds__(128) void scan2_kernel(int* __restrict__ btot,
                                                    int* __restrict__ row_ptr_n, int nb) {
  __shared__ int ws2[2];
  int tid = threadIdx.x, lane = tid & 63, wv = tid >> 6;
  int v = (tid < nb) ? btot[tid] : 0;
  int orig = v;
  for (int off = 1; off < 64; off <<= 1) {
    int t = __shfl_up(v, off);
    if (lane >= off) v += t;
  }
  if (lane == 63) ws2[wv] = v;
  __syncthreads();
  int wo = (wv == 1) ? ws2[0] : 0;
  if (tid < nb) btot[tid] = wo + v - orig;
  if (tid == nb - 1) *row_ptr_n = wo + v;
}

__global__ __launch_bounds__(512) void scan3_kernel(int* __restrict__ row_ptr,
                                                    int* __restrict__ cursor,
                                                    const int* __restrict__ btot, int n) {
  int i = blockIdx.x * 512 + threadIdx.x;
  if (i < n) {
    int v = row_ptr[i] + btot[blockIdx.x];
    row_ptr[i] = v;
    cursor[i] = v;
  }
}

__global__ void fill_kernel(const int* __restrict__ src, const int* __restrict__ dst,
                            int* __restrict__ cursor, int* __restrict__ csr_src,
                            int* __restrict__ csr_dst) {
  int e = blockIdx.x * blockDim.x + threadIdx.x;
  if (e < N_EDGES) {
    int d = dst[e];
    int p = atomicAdd(&cursor[d], 1);
    csr_src[p] = src[e];
    csr_dst[p] = d;
  }
}

// ---------------------------------------------------------------------------
// Edge-parallel softmax weights: w[h][p] = exp(leaky(ssrc[h][src]+sdst[h][dst]))
// ---------------------------------------------------------------------------
__global__ void weight_kernel(const float* __restrict__ ssrc,
                              const float* __restrict__ sdst,
                              const int* __restrict__ csr_src,
                              const int* __restrict__ csr_dst,
                              float* __restrict__ w) {
  int p = blockIdx.x * blockDim.x + threadIdx.x;
  if (p >= N_EDGES) return;
  int s = csr_src[p];
  int d = csr_dst[p];
#pragma unroll
  for (int h = 0; h < NH; h++) {
    float e = ssrc[h * N_NODES + s] + sdst[h * N_NODES + d];
    e = fmaxf(e, 0.01f * e);
    w[(size_t)h * N_EDGES + p] = __expf(e);
  }
}

// ---------------------------------------------------------------------------
// GAT layer 1 aggregation. Block = dst, wave = head, lanes 0..49 own a col
// pair. 8-deep unroll (R4 structure: best occupancy/ILP tradeoff).
// Output h1 as bf16 (feeds MFMA GEMM2).
// ---------------------------------------------------------------------------
__global__ __launch_bounds__(256) void agg1_kernel(const ushort* __restrict__ z,
                                                   const float* __restrict__ w,
                                                   const int* __restrict__ row_ptr,
                                                   const int* __restrict__ csr_src,
                                                   ushort* __restrict__ h1b) {
  const int d = blockIdx.x;
  const int h = threadIdx.x >> 6, lane = threadIdx.x & 63;
  const int beg = row_ptr[d], end = row_ptr[d + 1];
  const int deg = end - beg;
  uint* h1u = reinterpret_cast<uint*>(h1b);
  const size_t ou = (size_t)d * 200 + h * 50 + lane;  // uint offset
  bool act = lane < D1 / 2;  // 50 lanes
  if (deg == 0) {
    if (act) h1u[ou] = 0u;
    return;
  }
  const float* wh = w + (size_t)h * N_EDGES;
  float den = 0.f;
  for (int i = lane; i < deg; i += 64) den += wh[beg + i];
#pragma unroll
  for (int off = 32; off > 0; off >>= 1) den += __shfl_xor(den, off);

  if (!act) return;
  const uint* zb = reinterpret_cast<const uint*>(z);
  const int STR = NH * D1 / 2;  // 200 uints per row
  const int hco = h * (D1 / 2) + lane;
  float aE0 = 0.f, aE1 = 0.f, aE2 = 0.f, aE3 = 0.f;
  float aO0 = 0.f, aO1 = 0.f, aO2 = 0.f, aO3 = 0.f;
  int i = 0;
  for (; i + 8 <= deg; i += 8) {
    int s0 = csr_src[beg + i + 0], s1 = csr_src[beg + i + 1];
    int s2 = csr_src[beg + i + 2], s3 = csr_src[beg + i + 3];
    int s4 = csr_src[beg + i + 4], s5 = csr_src[beg + i + 5];
    int s6 = csr_src[beg + i + 6], s7 = csr_src[beg + i + 7];
    float x0 = wh[beg + i + 0], x1 = wh[beg + i + 1];
    float x2 = wh[beg + i + 2], x3 = wh[beg + i + 3];
    float x4 = wh[beg + i + 4], x5 = wh[beg + i + 5];
    float x6 = wh[beg + i + 6], x7 = wh[beg + i + 7];
    uint p0 = zb[(size_t)s0 * STR + hco];
    uint p1 = zb[(size_t)s1 * STR + hco];
    uint p2 = zb[(size_t)s2 * STR + hco];
    uint p3 = zb[(size_t)s3 * STR + hco];
    uint p4 = zb[(size_t)s4 * STR + hco];
    uint p5 = zb[(size_t)s5 * STR + hco];
    uint p6 = zb[(size_t)s6 * STR + hco];
    uint p7 = zb[(size_t)s7 * STR + hco];
    float lo, hi;
    bf16x2_unpack(p0, lo, hi); aE0 += x0 * lo; aO0 += x0 * hi;
    bf16x2_unpack(p1, lo, hi); aE1 += x1 * lo; aO1 += x1 * hi;
    bf16x2_unpack(p2, lo, hi); aE2 += x2 * lo; aO2 += x2 * hi;
    bf16x2_unpack(p3, lo, hi); aE3 += x3 * lo; aO3 += x3 * hi;
    bf16x2_unpack(p4, lo, hi); aE0 += x4 * lo; aO0 += x4 * hi;
    bf16x2_unpack(p5, lo, hi); aE1 += x5 * lo; aO1 += x5 * hi;
    bf16x2_unpack(p6, lo, hi); aE2 += x6 * lo; aO2 += x6 * hi;
    bf16x2_unpack(p7, lo, hi); aE3 += x7 * lo; aO3 += x7 * hi;
  }
  for (; i < deg; i++) {
    int s = csr_src[beg + i];
    float x = wh[beg + i];
    uint p = zb[(size_t)s * STR + hco];
    float lo, hi;
    bf16x2_unpack(p, lo, hi);
    aE0 += x * lo; aO0 += x * hi;
  }
  float inv = 1.0f / den;
  float vE = ((aE0 + aE1) + (aE2 + aE3)) * inv;
  float vO = ((aO0 + aO1) + (aO2 + aO3)) * inv;
  vE = vE > 0.f ? vE : 0.f;
  vO = vO > 0.f ? vO : 0.f;
  h1u[ou] = (uint)f2bf(vE) | ((uint)f2bf(vO) << 16);
}

// ---------------------------------------------------------------------------
// GAT layer 2 aggregation + head-mean + relu (writes h2 fp32).
// Wave = head; 6 edge-groups x 10 lanes (col pair each), 12-deep.
// ---------------------------------------------------------------------------
__global__ __launch_bounds__(256) void agg2_kernel(const ushort* __restrict__ z,
                                                   const float* __restrict__ w,
                                                   const int* __restrict__ row_ptr,
                                                   const int* __restrict__ csr_src,
                                                   float* __restrict__ h2) {
  __shared__ float hbuf[NH][D2];
  const int d = blockIdx.x;
  const int h = threadIdx.x >> 6, lane = threadIdx.x & 63;
  const int beg = row_ptr[d], end = row_ptr[d + 1];
  const int deg = end - beg;
  const int g = lane / 10;
  const int j = lane - g * 10;
  if (deg > 0) {
    const float* wh = w + (size_t)h * N_EDGES;
    float den = 0.f;
    for (int i = lane; i < deg; i += 64) den += wh[beg + i];
#pragma unroll
    for (int off = 32; off > 0; off >>= 1) den += __shfl_xor(den, off);

    const uint* zb = reinterpret_cast<const uint*>(z);
    const int STR2 = NH * D2 / 2;  // 40 uints per row
    const int hco = h * (D2 / 2) + j;
    float aE = 0.f, aO = 0.f;
    if (g < 6) {
      int i = g;
      for (; i + 6 < deg; i += 12) {
        int s0 = csr_src[beg + i];
        int s1 = csr_src[beg + i + 6];
        float x0 = wh[beg + i];
        float x1 = wh[beg + i + 6];
        uint p0 = zb[(size_t)s0 * STR2 + hco];
        uint p1 = zb[(size_t)s1 * STR2 + hco];
        float lo, hi;
        bf16x2_unpack(p0, lo, hi); aE += x0 * lo; aO += x0 * hi;
        bf16x2_unpack(p1, lo, hi); aE += x1 * lo; aO += x1 * hi;
      }
      if (i < deg) {
        int s = csr_src[beg + i];
        float x = wh[beg + i];
        uint p = zb[(size_t)s * STR2 + hco];
        float lo, hi;
        bf16x2_unpack(p, lo, hi);
        aE += x * lo;
        aO += x * hi;
      }
    }
    float tE = aE, tO = aO;
#pragma unroll
    for (int k = 1; k < 6; k++) {
      tE += __shfl(aE, lane + 10 * k);
      tO += __shfl(aO, lane + 10 * k);
    }
    if (lane < 10) {
      float invd = 1.0f / den;
      hbuf[h][2 * j] = tE * invd;
      hbuf[h][2 * j + 1] = tO * invd;
    }
  } else {
    if (lane < 10) {
      hbuf[h][2 * j] = 0.f;
      hbuf[h][2 * j + 1] = 0.f;
    }
  }
  __syncthreads();
  if (threadIdx.x < D2) {
    int c = threadIdx.x;
    float m = 0.25f * (hbuf[0][c] + hbuf[1][c] + hbuf[2][c] + hbuf[3][c]);
    h2[(size_t)d * D2 + c] = m > 0.f ? m : 0.f;
  }
}

// ---------------------------------------------------------------------------
// Graph mean-pool: wave-level pre-reduction (graph_id is sorted).
// ---------------------------------------------------------------------------
__global__ __launch_bounds__(256) void pool_kernel(const float* __restrict__ h2,
                                                   const int* __restrict__ gid,
                                                   float* __restrict__ hg,
                                                   int* __restrict__ gcnt) {
  int wave = threadIdx.x >> 6, lane = threadIdx.x & 63;
  int n = (blockIdx.x * 4 + wave) * 64 + lane;
  bool valid = n < N_NODES;
  int g = gid[valid ? n : (N_NODES - 1)];
  int g0 = __shfl(g, 0), g63 = __shfl(g, 63);
  unsigned long long mask = __ballot(valid);
  if (g0 == g63) {
    if (lane == 0) atomicAdd(&gcnt[g0], (int)__popcll(mask));
#pragma unroll
    for (int c = 0; c < D2; c++) {
      float v = valid ? h2[(size_t)n * D2 + c] : 0.f;
#pragma unroll
      for (int off = 32; off > 0; off >>= 1) v += __shfl_xor(v, off);
      if (lane == 0) atomicAdd(&hg[g0 * D2 + c], v);
    }
  } else if (valid) {
    atomicAdd(&gcnt[g], 1);
    for (int c = 0; c < D2; c++) atomicAdd(&hg[g * D2 + c], h2[(size_t)n * D2 + c]);
  }
}

// ---------------------------------------------------------------------------
// Readout MLP + BatchNorm + final projection in one block.
// ---------------------------------------------------------------------------
__global__ __launch_bounds__(256) void head_kernel(const float* __restrict__ hg,
                                                   const int* __restrict__ gcnt,
                                                   const float* __restrict__ Wf1,
                                                   const float* __restrict__ bf1,
                                                   const float* __restrict__ Wf2,
                                                   const float* __restrict__ bf2,
                                                   const float* __restrict__ Wf3,
                                                   const float* __restrict__ bf3,
                                                   const float* __restrict__ gamma,
                                                   const float* __restrict__ beta,
                                                   float* __restrict__ out) {
  __shared__ float X[NB][D2];
  __shared__ float T1[NB][128];
  __shared__ float T2[NB][32];
  __shared__ float scale_s[32], shift_s[32];
  int tid = threadIdx.x;
  for (int i = tid; i < NB * D2; i += 256) {
    int r = i / D2, c = i % D2;
    X[r][c] = hg[i] / (float)gcnt[r];
  }
  __syncthreads();
  for (int i = tid; i < NB * 128; i += 256) {
    int r = i >> 7, c = i & 127;
    float s = bf1[c];
#pragma unroll
    for (int k = 0; k < D2; k++) s += X[r][k] * Wf1[k * 128 + c];
    T1[r][c] = s > 0.f ? s : 0.f;
  }
  __syncthreads();
  for (int i = tid; i < NB * 32; i += 256) {
    int r = i >> 5, c = i & 31;
    float s = bf2[c];
#pragma unroll
    for (int k = 0; k < 128; k++) s += T1[r][k] * Wf2[k * 32 + c];
    T2[r][c] = s;
  }
  __syncthreads();
  if (tid < 32) {
    float mu = 0.f;
    for (int r = 0; r < NB; r++) mu += T2[r][tid];
    mu *= (1.f / NB);
    float var = 0.f;
    for (int r = 0; r < NB; r++) {
      float dv = T2[r][tid] - mu;
      var += dv * dv;
    }
    var *= (1.f / NB);
    float sc = gamma[tid] * rsqrtf(var + EPS_BN);
    scale_s[tid] = sc;
    shift_s[tid] = beta[tid] - mu * sc;
  }
  __syncthreads();
  if (tid < NB) {
    float s = bf3[0];
#pragma unroll
    for (int c = 0; c < 32; c++) {
      float y = scale_s[c] * T2[tid][c] + shift_s[c];
      y = y > 0.f ? y : 0.f;
      s += y * Wf3[c];
    }
    out[tid] = s;
  }
}

// ---------------------------------------------------------------------------

extern "C" void kernel_launch(void* const* d_in, const int* in_sizes, int n_in,
                              void* d_out, int out_size, void* d_ws, size_t ws_size,
                              hipStream_t stream) {
  const float* feat = (const float*)d_in[0];
  const int* src = (const int*)d_in[1];
  const int* dst = (const int*)d_in[2];
  const int* gid = (const int*)d_in[3];
  const float* W1 = (const float*)d_in[4];
  const float* a1 = (const float*)d_in[5];
  const float* W2 = (const float*)d_in[6];
  const float* a2 = (const float*)d_in[7];
  const float* Wf1 = (const float*)d_in[8];
  const float* bf1 = (const float*)d_in[9];
  const float* Wf2 = (const float*)d_in[10];
  const float* bf2 = (const float*)d_in[11];
  const float* Wf3 = (const float*)d_in[12];
  const float* bf3 = (const float*)d_in[13];
  const float* gamma2 = (const float*)d_in[14];
  const float* beta2 = (const float*)d_in[15];
  float* outp = (float*)d_out;

  char* p = (char*)d_ws;
  auto alloc = [&](size_t bytes) {
    void* q = (void*)p;
    p += (bytes + 255) & ~(size_t)255;
    return q;
  };
  ushort* z1b = (ushort*)alloc((size_t)N_NODES * NH * D1 * 2);   // 40 MB
  ushort* z2b = (ushort*)alloc((size_t)N_NODES * NH * D2 * 2);   // 8 MB
  ushort* h1b = (ushort*)alloc((size_t)N_NODES * NH * D1 * 2);   // 40 MB
  float* h2 = (float*)alloc((size_t)N_NODES * D2 * 4);           // 4 MB
  float* ssrc = (float*)alloc((size_t)NH * N_NODES * 4);
  float* sdst = (float*)alloc((size_t)NH * N_NODES * 4);
  float* wbuf = (float*)alloc((size_t)NH * N_EDGES * 4);         // 25.6 MB
  int* cnt = (int*)alloc((size_t)N_NODES * 4);
  int* row_ptr = (int*)alloc((size_t)(N_NODES + 1) * 4);
  int* cursor = (int*)alloc((size_t)N_NODES * 4);
  int* csr = (int*)alloc((size_t)N_EDGES * 4);
  int* csr_d = (int*)alloc((size_t)N_EDGES * 4);
  int* btot = (int*)alloc((size_t)128 * 4);
  ushort* B1t = (ushort*)alloc((size_t)NH * 128 * 128 * 2);      // 128 KB
  ushort* B2t = (ushort*)alloc((size_t)80 * 416 * 2);            // 66.6 KB
  float* hg = (float*)alloc((size_t)NB * D2 * 4);
  int* gcnt = (int*)alloc((size_t)NB * 4);

  const int rows64 = (N_NODES + 63) / 64;        // 782
  const int eblk = (N_EDGES + 255) / 256;        // 6250
  const int nblk = (N_NODES + 255) / 256;        // 196
  const int nhblk = (N_NODES * NH + 255) / 256;  // 782
  const int sblk = (N_NODES + 511) / 512;        // 98

  // CSR build
  hipMemsetAsync(cnt, 0, (size_t)N_NODES * 4, stream);
  hist_kernel<<<eblk, 256, 0, stream>>>(dst, cnt);
  scan1_kernel<<<sblk, 512, 0, stream>>>(cnt, row_ptr, btot, N_NODES);
  scan2_kernel<<<1, 128, 0, stream>>>(btot, row_ptr + N_NODES, sblk);
  scan3_kernel<<<sblk, 512, 0, stream>>>(row_ptr, cursor, btot, N_NODES);
  fill_kernel<<<eblk, 256, 0, stream>>>(src, dst, cursor, csr, csr_d);

  // Weight prep (independent)
  prep_b1t<<<256, 256, 0, stream>>>(W1, B1t);
  prep_b2t<<<130, 256, 0, stream>>>(W2, B2t);

  // Layer 1
  gemm1_mfma<<<dim3(rows64, NH), 256, 0, stream>>>(feat, B1t, z1b);
  scores_kernel<D1><<<nhblk, 256, 0, stream>>>(z1b, a1, ssrc, sdst);
  weight_kernel<<<eblk, 256, 0, stream>>>(ssrc, sdst, csr, csr_d, wbuf);
  agg1_kernel<<<N_NODES, 256, 0, stream>>>(z1b, wbuf, row_ptr, csr, h1b);

  // Layer 2
  gemm2_mfma<<<rows64, 256, 0, stream>>>(h1b, B2t, z2b);
  scores_kernel<D2><<<nhblk, 256, 0, stream>>>(z2b, a2, ssrc, sdst);
  weight_kernel<<<eblk, 256, 0, stream>>>(ssrc, sdst, csr, csr_d, wbuf);
  agg2_kernel<<<N_NODES, 256, 0, stream>>>(z2b, wbuf, row_ptr, csr, h2);

  // Readout
  hipMemsetAsync(hg, 0, (size_t)NB * D2 * 4, stream);
  hipMemsetAsync(gcnt, 0, (size_t)NB * 4, stream);
  pool_kernel<<<nblk, 256, 0, stream>>>(h2, gid, hg, gcnt);
  head_kernel<<<1, 256, 0, stream>>>(hg, gcnt, Wf1, bf1, Wf2, bf2, Wf3, bf3,
                                     gamma2, beta2, outp);
}

// Round 8
// 756.053 us; speedup vs baseline: 1.5901x; 1.0556x over previous
//
#include <hip/hip_runtime.h>
#include <hip/hip_bf16.h>
#include <math.h>

#define N_NODES 50000
#define N_EDGES 1600000
#define DIN 128
#define NH 4
#define D1 100
#define D2 20
#define NB 64
#define EPS_BN 1e-5f

// z1: [node][NH*D1=400] bf16 unpadded; z2: [node][NH*D2=80] bf16 unpadded
// h1: [node][400] bf16 (feeds MFMA GEMM2 directly)
// softmax weights computed inline in agg kernels (lane-parallel, LDS-staged)

typedef unsigned int uint;
typedef unsigned short ushort;
typedef short short8v __attribute__((ext_vector_type(8)));
typedef float float4v __attribute__((ext_vector_type(4)));

__device__ __forceinline__ void bf16x2_unpack(uint p, float& lo, float& hi) {
  lo = __uint_as_float(p << 16);
  hi = __uint_as_float(p & 0xffff0000u);
}

__device__ __forceinline__ ushort f2bf(float f) {  // RNE, finite inputs
  uint u = __float_as_uint(f);
  return (ushort)((u + 0x7fffu + ((u >> 16) & 1u)) >> 16);
}

// ---------------------------------------------------------------------------
// Prep: B1t[h][j][k] bf16 (j padded to 128) from W1[h][k][j] fp32
// ---------------------------------------------------------------------------
__global__ void prep_b1t(const float* __restrict__ W1, ushort* __restrict__ B1t) {
  int o = blockIdx.x * 256 + threadIdx.x;  // 4*128*128 = 65536
  int h = o >> 14;
  int r = o & 16383;
  int j = r >> 7, k = r & 127;
  float v = (j < D1) ? W1[((size_t)h * DIN + k) * D1 + j] : 0.f;
  B1t[o] = f2bf(v);
}

// ---------------------------------------------------------------------------
// Prep: B2t[c][k] bf16, c = h*20+j (80 cols), K padded 400->416 with zeros
// ---------------------------------------------------------------------------
__global__ void prep_b2t(const float* __restrict__ W2, ushort* __restrict__ B2t) {
  int idx = blockIdx.x * 256 + threadIdx.x;  // 80*416 = 33280
  if (idx >= 80 * 416) return;
  int c = idx / 416, k = idx - c * 416;
  int h = c / D2, j = c - h * D2;
  float v = (k < NH * D1) ? W2[((size_t)h * (NH * D1) + k) * D2 + j] : 0.f;
  B2t[idx] = f2bf(v);
}

// ---------------------------------------------------------------------------
// GEMM1 via bf16 MFMA 16x16x32: z1[row][h*100+j] = feat[row][:] . W1[h][:][j]
// ---------------------------------------------------------------------------
__global__ __launch_bounds__(256) void gemm1_mfma(const float* __restrict__ feat,
                                                  const ushort* __restrict__ B1t,
                                                  ushort* __restrict__ z1b) {
  __shared__ __align__(16) short As[64 * 136];
  __shared__ __align__(16) short Bs[128 * 136];
  const int row0 = blockIdx.x * 64;
  const int h = blockIdx.y;
  const int tid = threadIdx.x;
#pragma unroll
  for (int it = 0; it < 8; it++) {
    int idx = tid + it * 256;
    int r = idx >> 5, c4 = idx & 31;
    int row = row0 + r;
    float4 v = make_float4(0.f, 0.f, 0.f, 0.f);
    if (row < N_NODES) v = *reinterpret_cast<const float4*>(feat + (size_t)row * DIN + c4 * 4);
    short4 s;
    s.x = (short)f2bf(v.x); s.y = (short)f2bf(v.y);
    s.z = (short)f2bf(v.z); s.w = (short)f2bf(v.w);
    *reinterpret_cast<short4*>(&As[r * 136 + c4 * 4]) = s;
  }
  {
    const uint* bsrc = reinterpret_cast<const uint*>(B1t + (size_t)h * 16384);
#pragma unroll
    for (int it = 0; it < 32; it++) {
      int idx = tid + it * 256;
      int j = idx >> 6, kk = idx & 63;
      *reinterpret_cast<uint*>(&Bs[j * 136 + kk * 2]) = bsrc[idx];
    }
  }
  __syncthreads();
  const int wv = tid >> 6, lane = tid & 63;
  const int m = lane & 15, q = lane >> 4;
  float4v acc[8];
#pragma unroll
  for (int t = 0; t < 8; t++) acc[t] = (float4v){0.f, 0.f, 0.f, 0.f};
#pragma unroll
  for (int kq = 0; kq < 4; kq++) {
    short8v a = *reinterpret_cast<const short8v*>(&As[(wv * 16 + m) * 136 + kq * 32 + q * 8]);
#pragma unroll
    for (int t = 0; t < 8; t++) {
      short8v b = *reinterpret_cast<const short8v*>(&Bs[(t * 16 + m) * 136 + kq * 32 + q * 8]);
      acc[t] = __builtin_amdgcn_mfma_f32_16x16x32_bf16(a, b, acc[t], 0, 0, 0);
    }
  }
#pragma unroll
  for (int t = 0; t < 8; t++) {
    int cl = t * 16 + m;
    if (cl < D1) {
#pragma unroll
      for (int reg = 0; reg < 4; reg++) {
        int row = row0 + wv * 16 + q * 4 + reg;
        if (row < N_NODES) z1b[(size_t)row * (NH * D1) + h * D1 + cl] = f2bf(acc[t][reg]);
      }
    }
  }
}

// ---------------------------------------------------------------------------
// GEMM2 via bf16 MFMA: z2[row][c] = h1[row][:400] . B2t[c][:], c < 80.
// ---------------------------------------------------------------------------
__global__ __launch_bounds__(256) void gemm2_mfma(const ushort* __restrict__ h1b,
                                                  const ushort* __restrict__ B2t,
                                                  ushort* __restrict__ z2b) {
  __shared__ __align__(16) short As[64 * 40];
  __shared__ __align__(16) short Bs[80 * 40];
  const int row0 = blockIdx.x * 64;
  const int tid = threadIdx.x;
  const int wv = tid >> 6, lane = tid & 63;
  const int m = lane & 15, q = lane >> 4;
  const uint* au = reinterpret_cast<const uint*>(h1b);
  const uint* bu = reinterpret_cast<const uint*>(B2t);
  uint* asu = reinterpret_cast<uint*>(As);
  uint* bsu = reinterpret_cast<uint*>(Bs);
  float4v acc[5];
#pragma unroll
  for (int t = 0; t < 5; t++) acc[t] = (float4v){0.f, 0.f, 0.f, 0.f};
  for (int ch = 0; ch < 13; ch++) {
    int k0u = ch * 16;
    {
      int idx = tid;
#pragma unroll
      for (int it = 0; it < 4; it++, idx += 256) {
        int r = idx >> 4, ku = idx & 15;
        int row = row0 + r;
        uint v = 0;
        if (row < N_NODES && (k0u + ku) < 200) v = au[(size_t)row * 200 + k0u + ku];
        asu[r * 20 + ku] = v;
      }
      idx = tid;
#pragma unroll
      for (int it = 0; it < 5; it++, idx += 256) {
        int c = idx >> 4, ku = idx & 15;
        bsu[c * 20 + ku] = bu[(size_t)c * 208 + k0u + ku];
      }
    }
    __syncthreads();
    short8v a = *reinterpret_cast<const short8v*>(&As[(wv * 16 + m) * 40 + q * 8]);
#pragma unroll
    for (int t = 0; t < 5; t++) {
      short8v b = *reinterpret_cast<const short8v*>(&Bs[(t * 16 + m) * 40 + q * 8]);
      acc[t] = __builtin_amdgcn_mfma_f32_16x16x32_bf16(a, b, acc[t], 0, 0, 0);
    }
    __syncthreads();
  }
#pragma unroll
  for (int t = 0; t < 5; t++) {
    int col = t * 16 + m;
#pragma unroll
    for (int reg = 0; reg < 4; reg++) {
      int row = row0 + wv * 16 + q * 4 + reg;
      if (row < N_NODES) z2b[(size_t)row * (NH * D2) + col] = f2bf(acc[t][reg]);
    }
  }
}

// ---------------------------------------------------------------------------
// Attention scores from bf16 packed z (unpadded rows). Thread per (node,head).
// ---------------------------------------------------------------------------
template <int DOUT>
__global__ void scores_kernel(const ushort* __restrict__ z,
                              const float* __restrict__ a,
                              float* __restrict__ ssrc,
                              float* __restrict__ sdst) {
  int t = blockIdx.x * blockDim.x + threadIdx.x;
  if (t >= N_NODES * NH) return;
  int n = t >> 2;
  int h = t & 3;
  const uint* zr = reinterpret_cast<const uint*>(z) + (size_t)n * (NH * DOUT / 2) + h * (DOUT / 2);
  const float* as = a + h * 2 * DOUT;
  const float* ad = as + DOUT;
  float s1 = 0.f, s2 = 0.f;
  for (int j = 0; j < DOUT / 2; j++) {
    float lo, hi;
    bf16x2_unpack(zr[j], lo, hi);
    s1 += lo * as[2 * j] + hi * as[2 * j + 1];
    s2 += lo * ad[2 * j] + hi * ad[2 * j + 1];
  }
  ssrc[h * N_NODES + n] = s1;
  sdst[h * N_NODES + n] = s2;
}

// ---------------------------------------------------------------------------
// CSR build: histogram, 3-kernel hierarchical scan (+cursor), fill
// ---------------------------------------------------------------------------
__global__ void hist_kernel(const int* __restrict__ dst, int* __restrict__ cnt) {
  int e = blockIdx.x * blockDim.x + threadIdx.x;
  if (e < N_EDGES) atomicAdd(&cnt[dst[e]], 1);
}

__global__ __launch_bounds__(512) void scan1_kernel(const int* __restrict__ cnt,
                                                    int* __restrict__ row_ptr,
                                                    int* __restrict__ btot, int n) {
  __shared__ int ws[8];
  int b = blockIdx.x, tid = threadIdx.x, lane = tid & 63, wv = tid >> 6;
  int i = b * 512 + tid;
  int v = (i < n) ? cnt[i] : 0;
  int orig = v;
  for (int off = 1; off < 64; off <<= 1) {
    int t = __shfl_up(v, off);
    if (lane >= off) v += t;
  }
  if (lane == 63) ws[wv] = v;
  __syncthreads();
  int wo = 0;
  for (int j = 0; j < wv; j++) wo += ws[j];
  if (i < n) row_ptr[i] = wo + v - orig;
  if (tid == 511) btot[b] = wo + v;
}

__global__ __launch_bounds__(128) void scan2_kernel(int* __restrict__ btot,
                                                    int* __restrict__ row_ptr_n, int nb) {
  __shared__ int ws2[2];
  int tid = threadIdx.x, lane = tid & 63, wv = tid >> 6;
  int v = (tid < nb) ? btot[tid] : 0;
  int orig = v;
  for (int off = 1; off < 64; off <<= 1) {
    int t = __shfl_up(v, off);
    if (lane >= off) v += t;
  }
  if (lane == 63) ws2[wv] = v;
  __syncthreads();
  int wo = (wv == 1) ? ws2[0] : 0;
  if (tid < nb) btot[tid] = wo + v - orig;
  if (tid == nb - 1) *row_ptr_n = wo + v;
}

__global__ __launch_bounds__(512) void scan3_kernel(int* __restrict__ row_ptr,
                                                    int* __restrict__ cursor,
                                                    const int* __restrict__ btot, int n) {
  int i = blockIdx.x * 512 + threadIdx.x;
  if (i < n) {
    int v = row_ptr[i] + btot[blockIdx.x];
    row_ptr[i] = v;
    cursor[i] = v;
  }
}

__global__ void fill_kernel(const int* __restrict__ src, const int* __restrict__ dst,
                            int* __restrict__ cursor, int* __restrict__ csr_src) {
  int e = blockIdx.x * blockDim.x + threadIdx.x;
  if (e < N_EDGES) {
    int p = atomicAdd(&cursor[dst[e]], 1);
    csr_src[p] = src[e];
  }
}

// ---------------------------------------------------------------------------
// GAT layer 1 aggregation, weights fused. Block = dst, wave = head.
// Per 128-edge chunk: lane-parallel exp into per-wave LDS row (den inline),
// then 8-deep z-gather loop reading weights as LDS broadcasts.
// Output h1 bf16 (feeds MFMA GEMM2).
// ---------------------------------------------------------------------------
__global__ __launch_bounds__(256) void agg1_kernel(const ushort* __restrict__ z,
                                                   const float* __restrict__ ssrc,
                                                   const float* __restrict__ sdst,
                                                   const int* __restrict__ row_ptr,
                                                   const int* __restrict__ csr_src,
                                                   ushort* __restrict__ h1b) {
  __shared__ float lw[NH][128];
  const int d = blockIdx.x;
  const int h = threadIdx.x >> 6, lane = threadIdx.x & 63;
  const int beg = row_ptr[d], end = row_ptr[d + 1];
  const int deg = end - beg;
  uint* h1u = reinterpret_cast<uint*>(h1b);
  const size_t ou = (size_t)d * 200 + h * 50 + lane;
  const bool act = lane < D1 / 2;  // 50 lanes
  if (deg == 0) {
    if (act) h1u[ou] = 0u;
    return;
  }
  const int hN = h * N_NODES;
  const float sd = sdst[hN + d];
  const uint* zb = reinterpret_cast<const uint*>(z);
  const int hco = h * 50 + lane;  // used by act lanes only
  float den = 0.f;
  float aE0 = 0.f, aE1 = 0.f, aE2 = 0.f, aE3 = 0.f;
  float aO0 = 0.f, aO1 = 0.f, aO2 = 0.f, aO3 = 0.f;
  for (int c0 = 0; c0 < deg; c0 += 128) {
    const int cn = min(128, deg - c0);
    const int cb = beg + c0;
    // lane-parallel weight compute (ssrc gather is L2-resident: 200 KB/head)
    for (int i = lane; i < cn; i += 64) {
      int s = csr_src[cb + i];
      float e = ssrc[hN + s] + sd;
      e = fmaxf(e, 0.01f * e);
      float x = __expf(e);
      lw[h][i] = x;
      den += x;
    }
    if (act) {
      int j = 0;
      for (; j + 8 <= cn; j += 8) {
        int s0 = csr_src[cb + j + 0], s1 = csr_src[cb + j + 1];
        int s2 = csr_src[cb + j + 2], s3 = csr_src[cb + j + 3];
        int s4 = csr_src[cb + j + 4], s5 = csr_src[cb + j + 5];
        int s6 = csr_src[cb + j + 6], s7 = csr_src[cb + j + 7];
        float x0 = lw[h][j + 0], x1 = lw[h][j + 1];
        float x2 = lw[h][j + 2], x3 = lw[h][j + 3];
        float x4 = lw[h][j + 4], x5 = lw[h][j + 5];
        float x6 = lw[h][j + 6], x7 = lw[h][j + 7];
        uint p0 = zb[(size_t)s0 * 200 + hco];
        uint p1 = zb[(size_t)s1 * 200 + hco];
        uint p2 = zb[(size_t)s2 * 200 + hco];
        uint p3 = zb[(size_t)s3 * 200 + hco];
        uint p4 = zb[(size_t)s4 * 200 + hco];
        uint p5 = zb[(size_t)s5 * 200 + hco];
        uint p6 = zb[(size_t)s6 * 200 + hco];
        uint p7 = zb[(size_t)s7 * 200 + hco];
        float lo, hi;
        bf16x2_unpack(p0, lo, hi); aE0 += x0 * lo; aO0 += x0 * hi;
        bf16x2_unpack(p1, lo, hi); aE1 += x1 * lo; aO1 += x1 * hi;
        bf16x2_unpack(p2, lo, hi); aE2 += x2 * lo; aO2 += x2 * hi;
        bf16x2_unpack(p3, lo, hi); aE3 += x3 * lo; aO3 += x3 * hi;
        bf16x2_unpack(p4, lo, hi); aE0 += x4 * lo; aO0 += x4 * hi;
        bf16x2_unpack(p5, lo, hi); aE1 += x5 * lo; aO1 += x5 * hi;
        bf16x2_unpack(p6, lo, hi); aE2 += x6 * lo; aO2 += x6 * hi;
        bf16x2_unpack(p7, lo, hi); aE3 += x7 * lo; aO3 += x7 * hi;
      }
      for (; j < cn; j++) {
        int s = csr_src[cb + j];
        float x = lw[h][j];
        uint p = zb[(size_t)s * 200 + hco];
        float lo, hi;
        bf16x2_unpack(p, lo, hi);
        aE0 += x * lo;
        aO0 += x * hi;
      }
    }
  }
#pragma unroll
  for (int off = 32; off > 0; off >>= 1) den += __shfl_xor(den, off);
  if (!act) return;
  float inv = 1.0f / den;
  float vE = ((aE0 + aE1) + (aE2 + aE3)) * inv;
  float vO = ((aO0 + aO1) + (aO2 + aO3)) * inv;
  vE = vE > 0.f ? vE : 0.f;
  vO = vO > 0.f ? vO : 0.f;
  h1u[ou] = (uint)f2bf(vE) | ((uint)f2bf(vO) << 16);
}

// ---------------------------------------------------------------------------
// GAT layer 2 aggregation, weights fused, + head-mean + relu.
// Wave = head; per 128-edge chunk: lane-parallel exp to LDS, then
// 6 edge-groups x 10 lanes (col pair each) gather, 12-deep.
// ---------------------------------------------------------------------------
__global__ __launch_bounds__(256) void agg2_kernel(const ushort* __restrict__ z,
                                                   const float* __restrict__ ssrc,
                                                   const float* __restrict__ sdst,
                                                   const int* __restrict__ row_ptr,
                                                   const int* __restrict__ csr_src,
                                                   float* __restrict__ h2) {
  __shared__ float lw[NH][128];
  __shared__ float hbuf[NH][D2];
  const int d = blockIdx.x;
  const int h = threadIdx.x >> 6, lane = threadIdx.x & 63;
  const int beg = row_ptr[d], end = row_ptr[d + 1];
  const int deg = end - beg;
  const int g = lane / 10;
  const int j = lane - g * 10;
  if (deg > 0) {
    const int hN = h * N_NODES;
    const float sd = sdst[hN + d];
    const uint* zb = reinterpret_cast<const uint*>(z);
    const int hco = h * 10 + j;
    float den = 0.f, aE = 0.f, aO = 0.f;
    for (int c0 = 0; c0 < deg; c0 += 128) {
      const int cn = min(128, deg - c0);
      const int cb = beg + c0;
      for (int i = lane; i < cn; i += 64) {
        int s = csr_src[cb + i];
        float e = ssrc[hN + s] + sd;
        e = fmaxf(e, 0.01f * e);
        float x = __expf(e);
        lw[h][i] = x;
        den += x;
      }
      if (g < 6) {
        int i = g;
        for (; i + 6 < cn; i += 12) {
          int s0 = csr_src[cb + i];
          int s1 = csr_src[cb + i + 6];
          float x0 = lw[h][i];
          float x1 = lw[h][i + 6];
          uint p0 = zb[(size_t)s0 * 40 + hco];
          uint p1 = zb[(size_t)s1 * 40 + hco];
          float lo, hi;
          bf16x2_unpack(p0, lo, hi); aE += x0 * lo; aO += x0 * hi;
          bf16x2_unpack(p1, lo, hi); aE += x1 * lo; aO += x1 * hi;
        }
        if (i < cn) {
          int s = csr_src[cb + i];
          float x = lw[h][i];
          uint p = zb[(size_t)s * 40 + hco];
          float lo, hi;
          bf16x2_unpack(p, lo, hi);
          aE += x * lo;
          aO += x * hi;
        }
      }
    }
#pragma unroll
    for (int off = 32; off > 0; off >>= 1) den += __shfl_xor(den, off);
    float tE = aE, tO = aO;
#pragma unroll
    for (int k = 1; k < 6; k++) {
      tE += __shfl(aE, lane + 10 * k);
      tO += __shfl(aO, lane + 10 * k);
    }
    if (lane < 10) {
      float invd = 1.0f / den;
      hbuf[h][2 * j] = tE * invd;
      hbuf[h][2 * j + 1] = tO * invd;
    }
  } else {
    if (lane < 10) {
      hbuf[h][2 * j] = 0.f;
      hbuf[h][2 * j + 1] = 0.f;
    }
  }
  __syncthreads();
  if (threadIdx.x < D2) {
    int c = threadIdx.x;
    float m = 0.25f * (hbuf[0][c] + hbuf[1][c] + hbuf[2][c] + hbuf[3][c]);
    h2[(size_t)d * D2 + c] = m > 0.f ? m : 0.f;
  }
}

// ---------------------------------------------------------------------------
// Graph mean-pool: wave-level pre-reduction (graph_id is sorted).
// ---------------------------------------------------------------------------
__global__ __launch_bounds__(256) void pool_kernel(const float* __restrict__ h2,
                                                   const int* __restrict__ gid,
                                                   float* __restrict__ hg,
                                                   int* __restrict__ gcnt) {
  int wave = threadIdx.x >> 6, lane = threadIdx.x & 63;
  int n = (blockIdx.x * 4 + wave) * 64 + lane;
  bool valid = n < N_NODES;
  int g = gid[valid ? n : (N_NODES - 1)];
  int g0 = __shfl(g, 0), g63 = __shfl(g, 63);
  unsigned long long mask = __ballot(valid);
  if (g0 == g63) {
    if (lane == 0) atomicAdd(&gcnt[g0], (int)__popcll(mask));
#pragma unroll
    for (int c = 0; c < D2; c++) {
      float v = valid ? h2[(size_t)n * D2 + c] : 0.f;
#pragma unroll
      for (int off = 32; off > 0; off >>= 1) v += __shfl_xor(v, off);
      if (lane == 0) atomicAdd(&hg[g0 * D2 + c], v);
    }
  } else if (valid) {
    atomicAdd(&gcnt[g], 1);
    for (int c = 0; c < D2; c++) atomicAdd(&hg[g * D2 + c], h2[(size_t)n * D2 + c]);
  }
}

// ---------------------------------------------------------------------------
// Readout MLP + BatchNorm + final projection in one block.
// ---------------------------------------------------------------------------
__global__ __launch_bounds__(256) void head_kernel(const float* __restrict__ hg,
                                                   const int* __restrict__ gcnt,
                                                   const float* __restrict__ Wf1,
                                                   const float* __restrict__ bf1,
                                                   const float* __restrict__ Wf2,
                                                   const float* __restrict__ bf2,
                                                   const float* __restrict__ Wf3,
                                                   const float* __restrict__ bf3,
                                                   const float* __restrict__ gamma,
                                                   const float* __restrict__ beta,
                                                   float* __restrict__ out) {
  __shared__ float X[NB][D2];
  __shared__ float T1[NB][128];
  __shared__ float T2[NB][32];
  __shared__ float scale_s[32], shift_s[32];
  int tid = threadIdx.x;
  for (int i = tid; i < NB * D2; i += 256) {
    int r = i / D2, c = i % D2;
    X[r][c] = hg[i] / (float)gcnt[r];
  }
  __syncthreads();
  for (int i = tid; i < NB * 128; i += 256) {
    int r = i >> 7, c = i & 127;
    float s = bf1[c];
#pragma unroll
    for (int k = 0; k < D2; k++) s += X[r][k] * Wf1[k * 128 + c];
    T1[r][c] = s > 0.f ? s : 0.f;
  }
  __syncthreads();
  for (int i = tid; i < NB * 32; i += 256) {
    int r = i >> 5, c = i & 31;
    float s = bf2[c];
#pragma unroll
    for (int k = 0; k < 128; k++) s += T1[r][k] * Wf2[k * 32 + c];
    T2[r][c] = s;
  }
  __syncthreads();
  if (tid < 32) {
    float mu = 0.f;
    for (int r = 0; r < NB; r++) mu += T2[r][tid];
    mu *= (1.f / NB);
    float var = 0.f;
    for (int r = 0; r < NB; r++) {
      float dv = T2[r][tid] - mu;
      var += dv * dv;
    }
    var *= (1.f / NB);
    float sc = gamma[tid] * rsqrtf(var + EPS_BN);
    scale_s[tid] = sc;
    shift_s[tid] = beta[tid] - mu * sc;
  }
  __syncthreads();
  if (tid < NB) {
    float s = bf3[0];
#pragma unroll
    for (int c = 0; c < 32; c++) {
      float y = scale_s[c] * T2[tid][c] + shift_s[c];
      y = y > 0.f ? y : 0.f;
      s += y * Wf3[c];
    }
    out[tid] = s;
  }
}

// ---------------------------------------------------------------------------

extern "C" void kernel_launch(void* const* d_in, const int* in_sizes, int n_in,
                              void* d_out, int out_size, void* d_ws, size_t ws_size,
                              hipStream_t stream) {
  const float* feat = (const float*)d_in[0];
  const int* src = (const int*)d_in[1];
  const int* dst = (const int*)d_in[2];
  const int* gid = (const int*)d_in[3];
  const float* W1 = (const float*)d_in[4];
  const float* a1 = (const float*)d_in[5];
  const float* W2 = (const float*)d_in[6];
  const float* a2 = (const float*)d_in[7];
  const float* Wf1 = (const float*)d_in[8];
  const float* bf1 = (const float*)d_in[9];
  const float* Wf2 = (const float*)d_in[10];
  const float* bf2 = (const float*)d_in[11];
  const float* Wf3 = (const float*)d_in[12];
  const float* bf3 = (const float*)d_in[13];
  const float* gamma2 = (const float*)d_in[14];
  const float* beta2 = (const float*)d_in[15];
  float* outp = (float*)d_out;

  char* p = (char*)d_ws;
  auto alloc = [&](size_t bytes) {
    void* q = (void*)p;
    p += (bytes + 255) & ~(size_t)255;
    return q;
  };
  ushort* z1b = (ushort*)alloc((size_t)N_NODES * NH * D1 * 2);   // 40 MB
  ushort* z2b = (ushort*)alloc((size_t)N_NODES * NH * D2 * 2);   // 8 MB
  ushort* h1b = (ushort*)alloc((size_t)N_NODES * NH * D1 * 2);   // 40 MB
  float* h2 = (float*)alloc((size_t)N_NODES * D2 * 4);           // 4 MB
  float* ssrc = (float*)alloc((size_t)NH * N_NODES * 4);
  float* sdst = (float*)alloc((size_t)NH * N_NODES * 4);
  int* cnt = (int*)alloc((size_t)N_NODES * 4);
  int* row_ptr = (int*)alloc((size_t)(N_NODES + 1) * 4);
  int* cursor = (int*)alloc((size_t)N_NODES * 4);
  int* csr = (int*)alloc((size_t)N_EDGES * 4);
  int* btot = (int*)alloc((size_t)128 * 4);
  ushort* B1t = (ushort*)alloc((size_t)NH * 128 * 128 * 2);      // 128 KB
  ushort* B2t = (ushort*)alloc((size_t)80 * 416 * 2);            // 66.6 KB
  float* hg = (float*)alloc((size_t)NB * D2 * 4);
  int* gcnt = (int*)alloc((size_t)NB * 4);

  const int rows64 = (N_NODES + 63) / 64;        // 782
  const int eblk = (N_EDGES + 255) / 256;        // 6250
  const int nblk = (N_NODES + 255) / 256;        // 196
  const int nhblk = (N_NODES * NH + 255) / 256;  // 782
  const int sblk = (N_NODES + 511) / 512;        // 98

  // CSR build
  hipMemsetAsync(cnt, 0, (size_t)N_NODES * 4, stream);
  hist_kernel<<<eblk, 256, 0, stream>>>(dst, cnt);
  scan1_kernel<<<sblk, 512, 0, stream>>>(cnt, row_ptr, btot, N_NODES);
  scan2_kernel<<<1, 128, 0, stream>>>(btot, row_ptr + N_NODES, sblk);
  scan3_kernel<<<sblk, 512, 0, stream>>>(row_ptr, cursor, btot, N_NODES);
  fill_kernel<<<eblk, 256, 0, stream>>>(src, dst, cursor, csr);

  // Weight prep (independent)
  prep_b1t<<<256, 256, 0, stream>>>(W1, B1t);
  prep_b2t<<<130, 256, 0, stream>>>(W2, B2t);

  // Layer 1
  gemm1_mfma<<<dim3(rows64, NH), 256, 0, stream>>>(feat, B1t, z1b);
  scores_kernel<D1><<<nhblk, 256, 0, stream>>>(z1b, a1, ssrc, sdst);
  agg1_kernel<<<N_NODES, 256, 0, stream>>>(z1b, ssrc, sdst, row_ptr, csr, h1b);

  // Layer 2
  gemm2_mfma<<<rows64, 256, 0, stream>>>(h1b, B2t, z2b);
  scores_kernel<D2><<<nhblk, 256, 0, stream>>>(z2b, a2, ssrc, sdst);
  agg2_kernel<<<N_NODES, 256, 0, stream>>>(z2b, ssrc, sdst, row_ptr, csr, h2);

  // Readout
  hipMemsetAsync(hg, 0, (size_t)NB * D2 * 4, stream);
  hipMemsetAsync(gcnt, 0, (size_t)NB * 4, stream);
  pool_kernel<<<nblk, 256, 0, stream>>>(h2, gid, hg, gcnt);
  head_kernel<<<1, 256, 0, stream>>>(hg, gcnt, Wf1, bf1, Wf2, bf2, Wf3, bf3,
                                     gamma2, beta2, outp);
}